// Round 16
// baseline (6849.817 us; speedup 1.0000x reference)
//
#include <hip/hip_runtime.h>
#include <hip/hip_bf16.h>
#include <stdint.h>

typedef __attribute__((ext_vector_type(8))) short short8;
typedef __attribute__((ext_vector_type(4))) float f32x4;
typedef __attribute__((ext_vector_type(4))) int int4v;

__device__ __forceinline__ float bf2f(unsigned short u) {
  union { unsigned int i; float f; } v; v.i = ((unsigned int)u) << 16; return v.f;
}
__device__ __forceinline__ unsigned short f2bf(float f) {
  union { float f; unsigned int i; } v; v.f = f;
  unsigned int i = v.i;
  i += 0x7FFFu + ((i >> 16) & 1u);
  return (unsigned short)(i >> 16);
}
__device__ __forceinline__ float tanh_fast(float x) {
  float e = __expf(2.0f * x);
  return 1.0f - 2.0f / (e + 1.0f);
}
__device__ __forceinline__ uint32_t pack_pair(float v) {
  unsigned short hi = f2bf(v);
  unsigned short lo = f2bf(v - bf2f(hi));
  return (uint32_t)hi | ((uint32_t)lo << 16);
}

// ---------------- weight prep ----------------
// ODE: wimg[arr(hi/lo)][icb][oc][tap][icm] per layer (73728 elems/layer), bf16
// decoder (oc-contiguous): s1wt[kk][ic64][oc32], s2wt[kk][ic32][oc16], s3wt[kk][ic16]
__global__ void prep_weights(const float* __restrict__ w1, const float* __restrict__ w2,
                             const float* __restrict__ w3, const float* __restrict__ w4,
                             const float* __restrict__ s1w, const float* __restrict__ s2w,
                             const float* __restrict__ s3w,
                             unsigned short* __restrict__ wimg,
                             float* __restrict__ s1wt, float* __restrict__ s2wt,
                             float* __restrict__ s3wt) {
  int t = blockIdx.x * 256 + threadIdx.x;
  if (t < 147456) {
    int l = t / 36864;
    int oc = (t / 576) & 63;
    int ic = (t / 9) & 63;
    int tap = t % 9;
    const float* w = (l == 0) ? w1 : (l == 1) ? w2 : (l == 2) ? w3 : w4;
    float v = w[(oc * 64 + ic) * 9 + tap];
    unsigned short hi = f2bf(v);
    unsigned short lo = f2bf(v - bf2f(hi));
    int icb = ic >> 5, icm = ic & 31;
    int idx = (icb * 64 + oc) * 288 + tap * 32 + icm;
    wimg[l * 73728 + idx]         = hi;
    wimg[l * 73728 + 36864 + idx] = lo;
  } else if (t < 180224) {
    int u = t - 147456;                       // -> s1wt[(kk*64+ic)*32+oc]
    int oc = u & 31, ic = (u >> 5) & 63, kk = u >> 11;
    int ky = kk >> 2, kx = kk & 3;
    s1wt[(kk * 64 + ic) * 32 + oc] = s1w[((oc * 64 + ic) * 4 + ky) * 4 + kx];
  } else if (t < 188416) {
    int u = t - 180224;                       // -> s2wt[(kk*32+ic)*16+oc]
    int oc = u & 15, ic = (u >> 4) & 31, kk = u >> 9;
    int ky = kk >> 2, kx = kk & 3;
    s2wt[(kk * 32 + ic) * 16 + oc] = s2w[((oc * 32 + ic) * 4 + ky) * 4 + kx];
  } else if (t < 188560) {
    int u = t - 188416;                       // [kk][ic16]
    int ic = u & 15, kk = u >> 4;
    int ky = kk / 3, kx = kk % 3;
    s3wt[u] = s3w[ic * 9 + ky * 3 + kx];
  }
}

// NCHW h_s0 -> packed S0 + f32 outs[0]
__global__ void prep_state(const float* __restrict__ src,
                           uint32_t* __restrict__ s0, float* __restrict__ outs0) {
  int t = blockIdx.x * 256 + threadIdx.x;    // NHWC flat: ((b*32+h)*32+w)*64+c
  int c = t & 63, w = (t >> 6) & 31, h = (t >> 11) & 31, b = t >> 16;
  float v = src[((b * 64 + c) * 32 + h) * 32 + w];
  s0[t] = pack_pair(v);
  outs0[t] = v;
}

// ---------------- ODE conv body: 16 waves = K4 x (mt2 x nt2), wave = M32 x N32 -
// LDS: A[2 buf][arr2][pix136][chunk8]x16B (XOR swizzle)           -> 69632 B
//      RED[12 slot][q4][lane64] f32x4 (lane-contig, conflict-free) -> 49152 B
// B operands: per-lane 16B plain loads straight from wimg (L2-hot).
// State handoff: packed uint32, relaxed agent atomics (IC), NO fences.
// Own output rows -> A[next] in LDS at epilogue; only 2 halo rows staged.
#define A_BUF 34816
#define A_ARR 17408
#define REDB 69632
#define CONV_LDS 118784

__device__ __forceinline__ void slice_run(
    const uint8_t* A, const unsigned short* __restrict__ wimgL, int s,
    int mt, int lmod, int lg, int wo00, int wo01, int wo10, int wo11,
    f32x4& a00, f32x4& a01, f32x4& a10, f32x4& a11) {
  const int icb = (s >= 9) ? 1 : 0;
  const int tp = s - icb * 9;
  const int dy = tp / 3, dx = tp % 3;
  const int d = icb * 18432 + tp * 32;
  short8 bh0 = *(const short8*)(wimgL + wo00 + d);
  short8 bh1 = *(const short8*)(wimgL + wo01 + d);
  short8 bl0 = *(const short8*)(wimgL + wo10 + d);
  short8 bl1 = *(const short8*)(wimgL + wo11 + d);
  const int chunk = icb * 4 + lg;
  const int pix0 = (mt + dy) * 34 + (lmod + dx);
  const int pix1 = pix0 + 16;
  const int ab0 = pix0 * 128 + ((chunk ^ (pix0 & 7)) * 16);
  const int ab1 = pix1 * 128 + ((chunk ^ (pix1 & 7)) * 16);
  short8 ah0 = *(const short8*)(A + ab0);
  short8 al0 = *(const short8*)(A + A_ARR + ab0);
  short8 ah1 = *(const short8*)(A + ab1);
  short8 al1 = *(const short8*)(A + A_ARR + ab1);
  a00 = __builtin_amdgcn_mfma_f32_16x16x32_bf16(ah0, bh0, a00, 0, 0, 0);
  a00 = __builtin_amdgcn_mfma_f32_16x16x32_bf16(al0, bh0, a00, 0, 0, 0);
  a00 = __builtin_amdgcn_mfma_f32_16x16x32_bf16(ah0, bl0, a00, 0, 0, 0);
  a01 = __builtin_amdgcn_mfma_f32_16x16x32_bf16(ah0, bh1, a01, 0, 0, 0);
  a01 = __builtin_amdgcn_mfma_f32_16x16x32_bf16(al0, bh1, a01, 0, 0, 0);
  a01 = __builtin_amdgcn_mfma_f32_16x16x32_bf16(ah0, bl1, a01, 0, 0, 0);
  a10 = __builtin_amdgcn_mfma_f32_16x16x32_bf16(ah1, bh0, a10, 0, 0, 0);
  a10 = __builtin_amdgcn_mfma_f32_16x16x32_bf16(al1, bh0, a10, 0, 0, 0);
  a10 = __builtin_amdgcn_mfma_f32_16x16x32_bf16(ah1, bl0, a10, 0, 0, 0);
  a11 = __builtin_amdgcn_mfma_f32_16x16x32_bf16(ah1, bh1, a11, 0, 0, 0);
  a11 = __builtin_amdgcn_mfma_f32_16x16x32_bf16(al1, bh1, a11, 0, 0, 0);
  a11 = __builtin_amdgcn_mfma_f32_16x16x32_bf16(ah1, bl1, a11, 0, 0, 0);
}

__device__ __forceinline__ void conv_body(
    uint8_t* lds, int b, int h0, int cur, int full,
    const uint32_t* __restrict__ inP,
    const unsigned short* __restrict__ wimgL, const float* __restrict__ bias,
    uint32_t* __restrict__ outP,
    f32x4* Y, f32x4* R, float* __restrict__ outsPtr, int mode) {
  const int tid = threadIdx.x;
  uint8_t* A = lds + cur * A_BUF;
  uint8_t* An = lds + (cur ^ 1) * A_BUF;

  // ---- stage A rows from IC: full (4 rows, first conv) or halo rows {0,3}
  const int nitems = full ? 1088 : 544;
  for (int idx = tid; idx < nitems; idx += 1024) {
    int c = idx & 7;
    int w1 = (idx >> 3) % 34;
    int rsel = (idx >> 3) / 34;
    int row = full ? rsel : rsel * 3;         // halo: rows 0 and 3
    int hp = h0 - 1 + row;
    int w = w1 - 1;
    short8 hi8 = {0, 0, 0, 0, 0, 0, 0, 0};
    short8 lo8 = {0, 0, 0, 0, 0, 0, 0, 0};
    if (hp >= 0 && hp < 32 && w >= 0 && w < 32) {
      const uint64_t* sp = (const uint64_t*)(inP + (((b * 32 + hp) * 32 + w) * 64 + c * 8));
#pragma unroll
      for (int q = 0; q < 4; ++q) {
        uint64_t pk2 = __hip_atomic_load(sp + q, __ATOMIC_RELAXED,
                                         __HIP_MEMORY_SCOPE_AGENT);
        uint32_t p0 = (uint32_t)pk2, p1 = (uint32_t)(pk2 >> 32);
        hi8[q * 2]     = (short)(p0 & 0xFFFFu);
        lo8[q * 2]     = (short)(p0 >> 16);
        hi8[q * 2 + 1] = (short)(p1 & 0xFFFFu);
        lo8[q * 2 + 1] = (short)(p1 >> 16);
      }
    }
    const int pix = row * 34 + w1;
    const int off = pix * 128 + ((c ^ (pix & 7)) * 16);
    *(short8*)(A + off) = hi8;
    *(short8*)(A + A_ARR + off) = lo8;
  }
  __syncthreads();

  const int lane = tid & 63;
  const int wv = tid >> 6;                    // 0..15
  const int kq = wv >> 2;                     // K-quarter
  const int tl = wv & 3;
  const int mt = tl >> 1;                     // pixel half (rows)
  const int nt = tl & 1;                      // oc half
  const int lmod = lane & 15;
  const int lg = lane >> 4;

  // B global element-offsets (icb/tap delta added per slice)
  const int wo00 = (nt * 32 + lmod) * 288 + lg * 8;
  const int wo01 = wo00 + 16 * 288;
  const int wo10 = wo00 + 36864;
  const int wo11 = wo10 + 16 * 288;

  f32x4 a00 = {0.f,0.f,0.f,0.f}, a01 = {0.f,0.f,0.f,0.f};
  f32x4 a10 = {0.f,0.f,0.f,0.f}, a11 = {0.f,0.f,0.f,0.f};

  if (kq < 2) {
    const int s0 = kq * 5;
#pragma unroll
    for (int u = 0; u < 5; ++u)
      slice_run(A, wimgL, s0 + u, mt, lmod, lg, wo00, wo01, wo10, wo11,
                a00, a01, a10, a11);
  } else {
    const int s0 = 10 + (kq - 2) * 4;
#pragma unroll
    for (int u = 0; u < 4; ++u)
      slice_run(A, wimgL, s0 + u, mt, lmod, lg, wo00, wo01, wo10, wo11,
                a00, a01, a10, a11);
  }

  // ---- K-split partials: kq>0 write to RED[slot][q][lane] (conflict-free)
  if (kq > 0) {
    uint8_t* rb = lds + REDB + ((kq - 1) * 4 + tl) * 4096 + lane * 16;
    *(f32x4*)(rb)        = a00;
    *(f32x4*)(rb + 1024) = a01;
    *(f32x4*)(rb + 2048) = a10;
    *(f32x4*)(rb + 3072) = a11;
  }
  __syncthreads();

  if (kq == 0) {
#pragma unroll
    for (int p = 0; p < 3; ++p) {
      const uint8_t* rb = lds + REDB + (p * 4 + tl) * 4096 + lane * 16;
      a00 += *(const f32x4*)(rb);
      a01 += *(const f32x4*)(rb + 1024);
      a10 += *(const f32x4*)(rb + 2048);
      a11 += *(const f32x4*)(rb + 3072);
    }
    // ---- epilogue: quadrant q=(msub,nsub); px = mt*32+msub*16+lg*4+j
#pragma unroll
    for (int msub = 0; msub < 2; ++msub) {
#pragma unroll
      for (int nsub = 0; nsub < 2; ++nsub) {
        const int q = msub * 2 + nsub;
        f32x4 accv = (q == 0) ? a00 : (q == 1) ? a01 : (q == 2) ? a10 : a11;
        const int oc = nt * 32 + nsub * 16 + lmod;
        const float bz = bias[oc];
#pragma unroll
        for (int j = 0; j < 4; ++j) {
          const int px = mt * 32 + msub * 16 + lg * 4 + j;
          const int e = (b * 1024 + h0 * 32 + px) * 64 + oc;
          float kv = accv[j] + bz;
          float z;
          if (mode == 0) {                    // conv + tanh
            z = tanh_fast(kv);
          } else if (mode == 1) {             // k1: z=y+0.25k ; R=y+k/12
            z = fmaf(0.25f, kv, Y[q][j]);
            R[q][j] = fmaf(1.0f / 12.0f, kv, Y[q][j]);
          } else if (mode == 2 || mode == 3) { // k2/k3
            float cz = (mode == 2) ? 0.25f : 0.5f;
            z = fmaf(cz, kv, Y[q][j]);
            R[q][j] = fmaf(1.0f / 6.0f, kv, R[q][j]);
          } else {                            // k4: ynew = R + k/12
            z = fmaf(1.0f / 12.0f, kv, R[q][j]);
            Y[q][j] = z;
            if (outsPtr) outsPtr[e] = z;
          }
          uint32_t pk = pack_pair(z);
          __hip_atomic_store(&outP[e], pk, __ATOMIC_RELAXED,
                             __HIP_MEMORY_SCOPE_AGENT);
          const int pix = (1 + (px >> 5)) * 34 + (px & 31) + 1;
          const int off = pix * 128 + (((oc >> 3) ^ (pix & 7)) * 16) + (oc & 7) * 2;
          *(unsigned short*)(An + off)         = (unsigned short)(pk & 0xFFFFu);
          *(unsigned short*)(An + A_ARR + off) = (unsigned short)(pk >> 16);
        }
      }
    }
  }
}

// ---------------- persistent ODE kernel: 64 blocks x 16 waves, neighbor-sync ---
// __launch_bounds__(1024, 4): 4 waves/EU => 1 block/CU, VGPR budget 128
// (prevents the r8 silent clamp-to-64 + scratch spill).
__global__ __launch_bounds__(1024, 4) void ode_persist(
    const unsigned short* __restrict__ wimg,
    const float* __restrict__ b1, const float* __restrict__ b2,
    const float* __restrict__ b3, const float* __restrict__ b4,
    uint32_t* __restrict__ S0, uint32_t* __restrict__ S1,
    uint32_t* __restrict__ T0, uint32_t* __restrict__ T1,
    float* __restrict__ outs, int* progress) {
  extern __shared__ uint8_t lds[];
  const int blk = blockIdx.x;
  const int b = blk >> 4;
  const int rp = blk & 15;
  const int h0 = rp << 1;
  const int nbA = (rp > 0) ? blk - 1 : -1;
  const int nbB = (rp < 15) ? blk + 1 : -1;

  const unsigned short* Wl[4] = {wimg, wimg + 73728, wimg + 147456, wimg + 221184};
  const float* Bl[4] = {b1, b2, b3, b4};

  // zero pad columns (w1 = 0, 33) of epilogue-written rows 1,2 in BOTH A bufs
  if (threadIdx.x < 128) {
    int t = threadIdx.x;
    int chunk = t & 7;
    int col = ((t >> 3) & 1) * 33;
    int row = 1 + ((t >> 4) & 1);
    int arr = (t >> 5) & 1;
    int buf = (t >> 6) & 1;
    int pix = row * 34 + col;
    *(int4v*)(lds + buf * A_BUF + arr * A_ARR + pix * 128 +
              ((chunk ^ (pix & 7)) * 16)) = (int4v){0, 0, 0, 0};
  }
  __syncthreads();

  const int lane = threadIdx.x & 63;
  const int wv = threadIdx.x >> 6;
  const int kq = wv >> 2, tl = wv & 3;
  const int mt = tl >> 1, nt = tl & 1;
  const int lmod = lane & 15, lg = lane >> 4;
  f32x4 Y[4], R[4];
#pragma unroll
  for (int q = 0; q < 4; ++q) { Y[q] = (f32x4){0,0,0,0}; R[q] = (f32x4){0,0,0,0}; }
  if (kq == 0) {
#pragma unroll
    for (int msub = 0; msub < 2; ++msub)
#pragma unroll
      for (int nsub = 0; nsub < 2; ++nsub) {
        const int q = msub * 2 + nsub;
#pragma unroll
        for (int j = 0; j < 4; ++j) {
          const int px = mt * 32 + msub * 16 + lg * 4 + j;
          const int e = (b * 1024 + h0 * 32 + px) * 64 + nt * 32 + nsub * 16 + lmod;
          Y[q][j] = outs[e];
        }
      }
  }

  int done = 0;
  int cur = 0;
  for (int step = 1; step <= 18; ++step) {
    for (int sub = 0; sub < 4; ++sub) {
      for (int layer = 0; layer < 4; ++layer) {
        const uint32_t* inP;
        uint32_t* outP;
        int mode;
        float* op = nullptr;
        if (layer == 0) {
          inP = (sub == 0) ? S0 : S1; outP = T0; mode = 0;
        } else if (layer == 1) {
          inP = T0; outP = T1; mode = 0;
        } else if (layer == 2) {
          inP = T1; outP = T0; mode = 0;
        } else {
          inP = T0; outP = (sub == 3) ? S0 : S1; mode = 1 + sub;
          if (sub == 3 && (step & 1) == 0) op = outs + (size_t)(step >> 1) * 262144;
        }
        if (threadIdx.x == 0 && done > 0) {
          if (nbA >= 0)
            while (__hip_atomic_load(&progress[nbA], __ATOMIC_RELAXED,
                                     __HIP_MEMORY_SCOPE_AGENT) < done)
              __builtin_amdgcn_s_sleep(2);
          if (nbB >= 0)
            while (__hip_atomic_load(&progress[nbB], __ATOMIC_RELAXED,
                                     __HIP_MEMORY_SCOPE_AGENT) < done)
              __builtin_amdgcn_s_sleep(2);
        }
        __builtin_amdgcn_sched_barrier(0);
        __syncthreads();

        conv_body(lds, b, h0, cur, done == 0, inP, Wl[layer], Bl[layer], outP,
                  Y, R, op, mode);

        __syncthreads();                      // drains all waves' stores (vmcnt)
        ++done;
        cur ^= 1;
        if (threadIdx.x == 0) {
          __hip_atomic_store(&progress[blk], done, __ATOMIC_RELEASE,
                             __HIP_MEMORY_SCOPE_AGENT);
        }
      }
    }
  }
}

// ---------------- decoder: parity-specialized blocks, LDS weights -------------
__global__ __launch_bounds__(256) void dec_s1(const float* __restrict__ in,
                                              const float* __restrict__ wt,
                                              const float* __restrict__ bs,
                                              float* __restrict__ out) {
  __shared__ float wl[4][64][32];
  const int tid = threadIdx.x;
  const int bl = blockIdx.x & 127;
  const int par = (blockIdx.x >> 7) & 3;
  const int n = blockIdx.x >> 9;
  const int py = par >> 1, px = par & 1;
#pragma unroll
  for (int k = 0; k < 32; ++k) {
    int s = tid + k * 256;                    // 0..8191
    int oc_ = s & 31, ic = (s >> 5) & 63, tp = s >> 11;
    int kk = (py + 2 * (tp >> 1)) * 4 + (px + 2 * (tp & 1));
    wl[tp][ic][oc_] = wt[(kk * 64 + ic) * 32 + oc_];
  }
  __syncthreads();
  const int oc = tid & 31;
  const int pos = bl * 8 + (tid >> 5);
  const int my = pos >> 5, mx = pos & 31;
  float a = bs[oc];
#pragma unroll
  for (int ay = 0; ay < 2; ++ay) {
    int iy = my + py - 1 + ay;
    if ((unsigned)iy >= 32u) continue;
#pragma unroll
    for (int ax = 0; ax < 2; ++ax) {
      int ix = mx + px - 1 + ax;
      if ((unsigned)ix >= 32u) continue;
      const float4* xp = (const float4*)(in + ((n * 32 + iy) * 32 + ix) * 64);
      const int tp = ay * 2 + ax;
#pragma unroll
      for (int i4 = 0; i4 < 16; ++i4) {
        float4 xv = xp[i4];
        a = fmaf(xv.x, wl[tp][i4 * 4 + 0][oc], a);
        a = fmaf(xv.y, wl[tp][i4 * 4 + 1][oc], a);
        a = fmaf(xv.z, wl[tp][i4 * 4 + 2][oc], a);
        a = fmaf(xv.w, wl[tp][i4 * 4 + 3][oc], a);
      }
    }
  }
  const int oy = 2 * my + py, ox = 2 * mx + px;
  out[((n * 64 + oy) * 64 + ox) * 32 + oc] = (a > 0.f) ? a : 0.2f * a;
}

__global__ __launch_bounds__(256) void dec_s2(const float* __restrict__ in,
                                              const float* __restrict__ wt,
                                              const float* __restrict__ bs,
                                              float* __restrict__ out) {
  __shared__ float wl[4][32][16];
  const int tid = threadIdx.x;
  const int bl = blockIdx.x & 255;
  const int par = (blockIdx.x >> 8) & 3;
  const int n = blockIdx.x >> 10;
  const int py = par >> 1, px = par & 1;
#pragma unroll
  for (int k = 0; k < 8; ++k) {
    int s = tid + k * 256;                    // 0..2047
    int oc_ = s & 15, ic = (s >> 4) & 31, tp = s >> 9;
    int kk = (py + 2 * (tp >> 1)) * 4 + (px + 2 * (tp & 1));
    wl[tp][ic][oc_] = wt[(kk * 32 + ic) * 16 + oc_];
  }
  __syncthreads();
  const int oc = tid & 15;
  const int pos = bl * 16 + (tid >> 4);
  const int my = pos >> 6, mx = pos & 63;
  float a = bs[oc];
#pragma unroll
  for (int ay = 0; ay < 2; ++ay) {
    int iy = my + py - 1 + ay;
    if ((unsigned)iy >= 64u) continue;
#pragma unroll
    for (int ax = 0; ax < 2; ++ax) {
      int ix = mx + px - 1 + ax;
      if ((unsigned)ix >= 64u) continue;
      const float4* xp = (const float4*)(in + ((n * 64 + iy) * 64 + ix) * 32);
      const int tp = ay * 2 + ax;
#pragma unroll
      for (int i4 = 0; i4 < 8; ++i4) {
        float4 xv = xp[i4];
        a = fmaf(xv.x, wl[tp][i4 * 4 + 0][oc], a);
        a = fmaf(xv.y, wl[tp][i4 * 4 + 1][oc], a);
        a = fmaf(xv.z, wl[tp][i4 * 4 + 2][oc], a);
        a = fmaf(xv.w, wl[tp][i4 * 4 + 3][oc], a);
      }
    }
  }
  const int oy = 2 * my + py, ox = 2 * mx + px;
  out[((n * 128 + oy) * 128 + ox) * 16 + oc] = (a > 0.f) ? a : 0.2f * a;
}

__global__ __launch_bounds__(256) void dec_s3(const float* __restrict__ in,
                                              const float* __restrict__ wt,
                                              const float* __restrict__ bs,
                                              float* __restrict__ out) {
  int t = blockIdx.x * 256 + threadIdx.x;
  int ox = t & 127, oy = (t >> 7) & 127, n = t >> 14;
  float a = bs[0];
#pragma unroll
  for (int ky = 0; ky < 3; ++ky) {
    int iy = oy + ky - 1;
    if ((unsigned)iy >= 128u) continue;
#pragma unroll
    for (int kx = 0; kx < 3; ++kx) {
      int ix = ox + kx - 1;
      if ((unsigned)ix >= 128u) continue;
      const float4* xp = (const float4*)(in + ((n * 128 + iy) * 128 + ix) * 16);
      const float4* wp = (const float4*)(wt + (ky * 3 + kx) * 16);
#pragma unroll
      for (int i4 = 0; i4 < 4; ++i4) {
        float4 xv = xp[i4], wv = wp[i4];
        a = fmaf(xv.x, wv.x, a);
        a = fmaf(xv.y, wv.y, a);
        a = fmaf(xv.z, wv.z, a);
        a = fmaf(xv.w, wv.w, a);
      }
    }
  }
  out[n * 16384 + oy * 128 + ox] = a;
}

// ---------------- host ----------------
extern "C" void kernel_launch(void* const* d_in, const int* in_sizes, int n_in,
                              void* d_out, int out_size, void* d_ws, size_t ws_size,
                              hipStream_t stream) {
  (void)in_sizes; (void)n_in; (void)out_size; (void)ws_size;
  (void)hipFuncSetAttribute((const void*)ode_persist,
                            hipFuncAttributeMaxDynamicSharedMemorySize, CONV_LDS);

  uint8_t* ws = (uint8_t*)d_ws;
  uint32_t* S0 = (uint32_t*)(ws + 0);         // packed state, 1 MB each
  uint32_t* S1 = (uint32_t*)(ws + 1048576);
  uint32_t* T0 = (uint32_t*)(ws + 2097152);
  uint32_t* T1 = (uint32_t*)(ws + 3145728);
  unsigned short* WIMG = (unsigned short*)(ws + 4194304);   // 589824 B
  float* s1wt = (float*)(ws + 4784128);
  float* s2wt = (float*)(ws + 4915200);
  float* s3wt = (float*)(ws + 4947968);
  int* progress = (int*)(ws + 4980736);       // 64 x int
  float* outs = (float*)(ws + 5242880);       // 10 x 262144 f32
  float* d1 = (float*)(ws + 16777216);        // decoder scratch 2 MB
  float* d2 = (float*)(ws + 18874368);        // decoder scratch 4 MB

  const float* h_s0 = (const float*)d_in[0];
  const float* wode[4] = {(const float*)d_in[1], (const float*)d_in[3],
                          (const float*)d_in[5], (const float*)d_in[7]};
  const float* bode[4] = {(const float*)d_in[2], (const float*)d_in[4],
                          (const float*)d_in[6], (const float*)d_in[8]};
  const float* s1w = (const float*)d_in[9];
  const float* s1b = (const float*)d_in[10];
  const float* s2w = (const float*)d_in[11];
  const float* s2b = (const float*)d_in[12];
  const float* s3w = (const float*)d_in[13];
  const float* s3b = (const float*)d_in[14];

  (void)hipMemsetAsync(progress, 0, 64 * sizeof(int), stream);
  prep_weights<<<737, 256, 0, stream>>>(wode[0], wode[1], wode[2], wode[3],
                                        s1w, s2w, s3w, WIMG, s1wt, s2wt, s3wt);
  prep_state<<<1024, 256, 0, stream>>>(h_s0, S0, outs);

  ode_persist<<<dim3(64), dim3(1024), CONV_LDS, stream>>>(
      WIMG, bode[0], bode[1], bode[2], bode[3],
      S0, S1, T0, T1, outs, progress);

  for (int t0 = 0; t0 < 10; ++t0) {
    dec_s1<<<2048, 256, 0, stream>>>(outs + (size_t)t0 * 262144, s1wt, s1b, d1);
    dec_s2<<<4096, 256, 0, stream>>>(d1, s2wt, s2b, d2);
    dec_s3<<<256, 256, 0, stream>>>(d2, s3wt, s3b,
                                    (float*)d_out + (size_t)t0 * 65536);
  }
}

// Round 17
// 4181.562 us; speedup vs baseline: 1.6381x; 1.6381x over previous
//
#include <hip/hip_runtime.h>
#include <hip/hip_bf16.h>
#include <stdint.h>

typedef __attribute__((ext_vector_type(8))) short short8;
typedef __attribute__((ext_vector_type(4))) float f32x4;
typedef __attribute__((ext_vector_type(4))) int int4v;

__device__ __forceinline__ float bf2f(unsigned short u) {
  union { unsigned int i; float f; } v; v.i = ((unsigned int)u) << 16; return v.f;
}
__device__ __forceinline__ unsigned short f2bf(float f) {
  union { float f; unsigned int i; } v; v.f = f;
  unsigned int i = v.i;
  i += 0x7FFFu + ((i >> 16) & 1u);
  return (unsigned short)(i >> 16);
}
__device__ __forceinline__ float tanh_fast(float x) {
  float e = __expf(2.0f * x);
  return 1.0f - 2.0f / (e + 1.0f);
}
__device__ __forceinline__ uint32_t pack_pair(float v) {
  unsigned short hi = f2bf(v);
  unsigned short lo = f2bf(v - bf2f(hi));
  return (uint32_t)hi | ((uint32_t)lo << 16);
}

// ---------------- weight prep ----------------
// ODE: wimg[arr(hi/lo)][icb][oc][tap][icm] per layer (73728 elems/layer), bf16
// decoder (oc-contiguous): s1wt[kk][ic64][oc32], s2wt[kk][ic32][oc16], s3wt[kk][ic16]
__global__ void prep_weights(const float* __restrict__ w1, const float* __restrict__ w2,
                             const float* __restrict__ w3, const float* __restrict__ w4,
                             const float* __restrict__ s1w, const float* __restrict__ s2w,
                             const float* __restrict__ s3w,
                             unsigned short* __restrict__ wimg,
                             float* __restrict__ s1wt, float* __restrict__ s2wt,
                             float* __restrict__ s3wt) {
  int t = blockIdx.x * 256 + threadIdx.x;
  if (t < 147456) {
    int l = t / 36864;
    int oc = (t / 576) & 63;
    int ic = (t / 9) & 63;
    int tap = t % 9;
    const float* w = (l == 0) ? w1 : (l == 1) ? w2 : (l == 2) ? w3 : w4;
    float v = w[(oc * 64 + ic) * 9 + tap];
    unsigned short hi = f2bf(v);
    unsigned short lo = f2bf(v - bf2f(hi));
    int icb = ic >> 5, icm = ic & 31;
    int idx = (icb * 64 + oc) * 288 + tap * 32 + icm;
    wimg[l * 73728 + idx]         = hi;
    wimg[l * 73728 + 36864 + idx] = lo;
  } else if (t < 180224) {
    int u = t - 147456;                       // -> s1wt[(kk*64+ic)*32+oc]
    int oc = u & 31, ic = (u >> 5) & 63, kk = u >> 11;
    int ky = kk >> 2, kx = kk & 3;
    s1wt[(kk * 64 + ic) * 32 + oc] = s1w[((oc * 64 + ic) * 4 + ky) * 4 + kx];
  } else if (t < 188416) {
    int u = t - 180224;                       // -> s2wt[(kk*32+ic)*16+oc]
    int oc = u & 15, ic = (u >> 4) & 31, kk = u >> 9;
    int ky = kk >> 2, kx = kk & 3;
    s2wt[(kk * 32 + ic) * 16 + oc] = s2w[((oc * 32 + ic) * 4 + ky) * 4 + kx];
  } else if (t < 188560) {
    int u = t - 188416;                       // [kk][ic16]
    int ic = u & 15, kk = u >> 4;
    int ky = kk / 3, kx = kk % 3;
    s3wt[u] = s3w[ic * 9 + ky * 3 + kx];
  }
}

// NCHW h_s0 -> packed S0 + f32 outs[0]
__global__ void prep_state(const float* __restrict__ src,
                           uint32_t* __restrict__ s0, float* __restrict__ outs0) {
  int t = blockIdx.x * 256 + threadIdx.x;    // NHWC flat: ((b*32+h)*32+w)*64+c
  int c = t & 63, w = (t >> 6) & 31, h = (t >> 11) & 31, b = t >> 16;
  float v = src[((b * 64 + c) * 32 + h) * 32 + w];
  s0[t] = pack_pair(v);
  outs0[t] = v;
}

// ---------------- ODE conv body (1024 thr, 16 waves; wave = M16 x N16) --------
// LDS: A[2 buf][arr2][pix136][chunk8]x16B (XOR swizzle) -> 69632 B total.
// W operands: per-lane 16B plain loads straight from wimg (L1/L2-hot; r16
// verified conflict-free + no HBM cost). No W staging, no mid-conv barriers.
// State handoff: packed uint32, relaxed agent atomics (IC), NO fences.
// Own output rows -> A[next] in LDS at epilogue; only 2 halo rows staged.
#define A_BUF 34816
#define A_ARR 17408
#define CONV_LDS 69632

__device__ __forceinline__ void conv_body(
    uint8_t* lds, int b, int h0, int cur, int full,
    const uint32_t* __restrict__ inP,
    const unsigned short* __restrict__ wimgL, const float* __restrict__ bias,
    uint32_t* __restrict__ outP,
    float* Y, float* R, float* __restrict__ outsPtr, int mode) {
  const int tid = threadIdx.x;
  uint8_t* A = lds + cur * A_BUF;
  uint8_t* An = lds + (cur ^ 1) * A_BUF;

  // ---- stage A rows from IC: full (4 rows, first conv) or halo rows {0,3}
  const int nitems = full ? 1088 : 544;
  for (int idx = tid; idx < nitems; idx += 1024) {
    int c = idx & 7;
    int w1 = (idx >> 3) % 34;
    int rsel = (idx >> 3) / 34;
    int row = full ? rsel : rsel * 3;         // halo: rows 0 and 3
    int hp = h0 - 1 + row;
    int w = w1 - 1;
    short8 hi8 = {0, 0, 0, 0, 0, 0, 0, 0};
    short8 lo8 = {0, 0, 0, 0, 0, 0, 0, 0};
    if (hp >= 0 && hp < 32 && w >= 0 && w < 32) {
      const uint64_t* sp = (const uint64_t*)(inP + (((b * 32 + hp) * 32 + w) * 64 + c * 8));
#pragma unroll
      for (int q = 0; q < 4; ++q) {
        uint64_t pk2 = __hip_atomic_load(sp + q, __ATOMIC_RELAXED,
                                         __HIP_MEMORY_SCOPE_AGENT);
        uint32_t p0 = (uint32_t)pk2, p1 = (uint32_t)(pk2 >> 32);
        hi8[q * 2]     = (short)(p0 & 0xFFFFu);
        lo8[q * 2]     = (short)(p0 >> 16);
        hi8[q * 2 + 1] = (short)(p1 & 0xFFFFu);
        lo8[q * 2 + 1] = (short)(p1 >> 16);
      }
    }
    const int pix = row * 34 + w1;
    const int off = pix * 128 + ((c ^ (pix & 7)) * 16);
    *(short8*)(A + off) = hi8;
    *(short8*)(A + A_ARR + off) = lo8;
  }
  __syncthreads();

  const int lane = tid & 63;
  const int wv = tid >> 6;                    // 0..15
  const int mq = wv & 3;                      // M16 quarter
  const int ng = wv >> 2;                     // N16 group
  const int lmod = lane & 15;
  const int lg = lane >> 4;
  const int P = mq * 16 + lmod;               // A pixel (m = lane&15)
  const int r = P >> 5;
  const int c0 = P & 31;
  const int oc = ng * 16 + lmod;
  const int wo = oc * 288 + lg * 8;           // + icb*18432 + tap*32 (hi); +36864 lo

  f32x4 acc = (f32x4){0.f, 0.f, 0.f, 0.f};

#pragma unroll
  for (int icb = 0; icb < 2; ++icb) {
#pragma unroll
    for (int tap = 0; tap < 9; ++tap) {
      const int dy = tap / 3, dx = tap % 3;
      const int pix = (r + dy) * 34 + (c0 + dx);
      const int chunk = icb * 4 + lg;
      const int abyte = pix * 128 + ((chunk ^ (pix & 7)) * 16);
      short8 ah = *(const short8*)(A + abyte);
      short8 al = *(const short8*)(A + A_ARR + abyte);
      const int d = icb * 18432 + tap * 32;
      short8 bh = *(const short8*)(wimgL + wo + d);
      short8 bl = *(const short8*)(wimgL + wo + 36864 + d);
      acc = __builtin_amdgcn_mfma_f32_16x16x32_bf16(ah, bh, acc, 0, 0, 0);
      acc = __builtin_amdgcn_mfma_f32_16x16x32_bf16(al, bh, acc, 0, 0, 0);
      acc = __builtin_amdgcn_mfma_f32_16x16x32_bf16(ah, bl, acc, 0, 0, 0);
    }
  }

  // ---- epilogue: D[m=(lane>>4)*4+j][n=lane&15]; px = mq*16+m, oc = ng*16+n
  //      write z: packed -> global (for neighbor halo) AND own rows -> A[next]
  const float bz = bias[oc];
#pragma unroll
  for (int j = 0; j < 4; ++j) {
    const int px = mq * 16 + lg * 4 + j;
    const int e = (b * 1024 + h0 * 32 + px) * 64 + oc;
    float kv = acc[j] + bz;
    float z;
    if (mode == 0) {                          // conv + tanh
      z = tanh_fast(kv);
    } else if (mode == 1) {                   // k1: z=y+0.25k ; R=y+k/12
      z = fmaf(0.25f, kv, Y[j]);
      R[j] = fmaf(1.0f / 12.0f, kv, Y[j]);
    } else if (mode == 2 || mode == 3) {      // k2/k3
      float cz = (mode == 2) ? 0.25f : 0.5f;
      z = fmaf(cz, kv, Y[j]);
      R[j] = fmaf(1.0f / 6.0f, kv, R[j]);
    } else {                                  // k4: ynew = R + k/12
      z = fmaf(1.0f / 12.0f, kv, R[j]);
      Y[j] = z;
      if (outsPtr) outsPtr[e] = z;
    }
    uint32_t pk = pack_pair(z);
    __hip_atomic_store(&outP[e], pk, __ATOMIC_RELAXED, __HIP_MEMORY_SCOPE_AGENT);
    // own rows into A[next]: tile row = 1 + (px>>5), w1 = (px&31)+1
    const int pix = (1 + (px >> 5)) * 34 + (px & 31) + 1;
    const int off = pix * 128 + (((oc >> 3) ^ (pix & 7)) * 16) + (oc & 7) * 2;
    *(unsigned short*)(An + off)         = (unsigned short)(pk & 0xFFFFu);
    *(unsigned short*)(An + A_ARR + off) = (unsigned short)(pk >> 16);
  }
}

// ---------------- persistent ODE kernel: 64 blocks x 16 waves, neighbor-sync ---
// grid 64 = 4 batch x 16 row-pairs; 1 block/CU, 4 waves/SIMD.
// progress[blk] = convs completed (RELEASE after barrier drains stores to IC).
// Waiters spin with RELAXED loads. Lockstep bound: co-executing blocks are at
// the SAME conv index; write buffer != read buffer (S->T0->T1->T0->S).
__global__ __launch_bounds__(1024) void ode_persist(
    const unsigned short* __restrict__ wimg,
    const float* __restrict__ b1, const float* __restrict__ b2,
    const float* __restrict__ b3, const float* __restrict__ b4,
    uint32_t* __restrict__ S0, uint32_t* __restrict__ S1,
    uint32_t* __restrict__ T0, uint32_t* __restrict__ T1,
    float* __restrict__ outs, int* progress) {
  extern __shared__ uint8_t lds[];
  const int blk = blockIdx.x;
  const int b = blk >> 4;
  const int rp = blk & 15;
  const int h0 = rp << 1;
  const int nbA = (rp > 0) ? blk - 1 : -1;
  const int nbB = (rp < 15) ? blk + 1 : -1;

  const unsigned short* Wl[4] = {wimg, wimg + 73728, wimg + 147456, wimg + 221184};
  const float* Bl[4] = {b1, b2, b3, b4};

  // zero pad columns (w1 = 0, 33) of epilogue-written rows 1,2 in BOTH A bufs
  if (threadIdx.x < 128) {
    int t = threadIdx.x;
    int chunk = t & 7;
    int col = ((t >> 3) & 1) * 33;
    int row = 1 + ((t >> 4) & 1);
    int arr = (t >> 5) & 1;
    int buf = (t >> 6) & 1;
    int pix = row * 34 + col;
    *(int4v*)(lds + buf * A_BUF + arr * A_ARR + pix * 128 +
              ((chunk ^ (pix & 7)) * 16)) = (int4v){0, 0, 0, 0};
  }
  __syncthreads();

  // per-thread RK4 state: 4 outputs at (px = mq*16+lg*4+j, oc = ng*16+lmod)
  const int lane = threadIdx.x & 63;
  const int wv = threadIdx.x >> 6;
  const int mq = wv & 3, ng = wv >> 2;
  const int lmod = lane & 15, lg = lane >> 4;
  float Y[4], R[4];
#pragma unroll
  for (int j = 0; j < 4; ++j) {
    const int e = (b * 1024 + h0 * 32 + mq * 16 + lg * 4 + j) * 64 + ng * 16 + lmod;
    Y[j] = outs[e];                           // exact f32 initial state
    R[j] = 0.f;
  }

  int done = 0;
  int cur = 0;
  for (int step = 1; step <= 18; ++step) {
    for (int sub = 0; sub < 4; ++sub) {
      for (int layer = 0; layer < 4; ++layer) {
        const uint32_t* inP;
        uint32_t* outP;
        int mode;
        float* op = nullptr;
        if (layer == 0) {
          inP = (sub == 0) ? S0 : S1; outP = T0; mode = 0;
        } else if (layer == 1) {
          inP = T0; outP = T1; mode = 0;
        } else if (layer == 2) {
          inP = T1; outP = T0; mode = 0;
        } else {
          inP = T0; outP = (sub == 3) ? S0 : S1; mode = 1 + sub;
          if (sub == 3 && (step & 1) == 0) op = outs + (size_t)(step >> 1) * 262144;
        }
        if (threadIdx.x == 0 && done > 0) {
          if (nbA >= 0)
            while (__hip_atomic_load(&progress[nbA], __ATOMIC_RELAXED,
                                     __HIP_MEMORY_SCOPE_AGENT) < done)
              __builtin_amdgcn_s_sleep(2);
          if (nbB >= 0)
            while (__hip_atomic_load(&progress[nbB], __ATOMIC_RELAXED,
                                     __HIP_MEMORY_SCOPE_AGENT) < done)
              __builtin_amdgcn_s_sleep(2);
        }
        __builtin_amdgcn_sched_barrier(0);
        __syncthreads();

        conv_body(lds, b, h0, cur, done == 0, inP, Wl[layer], Bl[layer], outP,
                  Y, R, op, mode);

        __syncthreads();                      // drains all waves' stores (vmcnt)
        ++done;
        cur ^= 1;
        if (threadIdx.x == 0) {
          __hip_atomic_store(&progress[blk], done, __ATOMIC_RELEASE,
                             __HIP_MEMORY_SCOPE_AGENT);
        }
      }
    }
  }
}

// ---------------- decoder: parity-specialized blocks, LDS weights -------------
__global__ __launch_bounds__(256) void dec_s1(const float* __restrict__ in,
                                              const float* __restrict__ wt,
                                              const float* __restrict__ bs,
                                              float* __restrict__ out) {
  __shared__ float wl[4][64][32];
  const int tid = threadIdx.x;
  const int bl = blockIdx.x & 127;
  const int par = (blockIdx.x >> 7) & 3;
  const int n = blockIdx.x >> 9;
  const int py = par >> 1, px = par & 1;
#pragma unroll
  for (int k = 0; k < 32; ++k) {
    int s = tid + k * 256;                    // 0..8191
    int oc_ = s & 31, ic = (s >> 5) & 63, tp = s >> 11;
    int kk = (py + 2 * (tp >> 1)) * 4 + (px + 2 * (tp & 1));
    wl[tp][ic][oc_] = wt[(kk * 64 + ic) * 32 + oc_];
  }
  __syncthreads();
  const int oc = tid & 31;
  const int pos = bl * 8 + (tid >> 5);
  const int my = pos >> 5, mx = pos & 31;
  float a = bs[oc];
#pragma unroll
  for (int ay = 0; ay < 2; ++ay) {
    int iy = my + py - 1 + ay;
    if ((unsigned)iy >= 32u) continue;
#pragma unroll
    for (int ax = 0; ax < 2; ++ax) {
      int ix = mx + px - 1 + ax;
      if ((unsigned)ix >= 32u) continue;
      const float4* xp = (const float4*)(in + ((n * 32 + iy) * 32 + ix) * 64);
      const int tp = ay * 2 + ax;
#pragma unroll
      for (int i4 = 0; i4 < 16; ++i4) {
        float4 xv = xp[i4];
        a = fmaf(xv.x, wl[tp][i4 * 4 + 0][oc], a);
        a = fmaf(xv.y, wl[tp][i4 * 4 + 1][oc], a);
        a = fmaf(xv.z, wl[tp][i4 * 4 + 2][oc], a);
        a = fmaf(xv.w, wl[tp][i4 * 4 + 3][oc], a);
      }
    }
  }
  const int oy = 2 * my + py, ox = 2 * mx + px;
  out[((n * 64 + oy) * 64 + ox) * 32 + oc] = (a > 0.f) ? a : 0.2f * a;
}

__global__ __launch_bounds__(256) void dec_s2(const float* __restrict__ in,
                                              const float* __restrict__ wt,
                                              const float* __restrict__ bs,
                                              float* __restrict__ out) {
  __shared__ float wl[4][32][16];
  const int tid = threadIdx.x;
  const int bl = blockIdx.x & 255;
  const int par = (blockIdx.x >> 8) & 3;
  const int n = blockIdx.x >> 10;
  const int py = par >> 1, px = par & 1;
#pragma unroll
  for (int k = 0; k < 8; ++k) {
    int s = tid + k * 256;                    // 0..2047
    int oc_ = s & 15, ic = (s >> 4) & 31, tp = s >> 9;
    int kk = (py + 2 * (tp >> 1)) * 4 + (px + 2 * (tp & 1));
    wl[tp][ic][oc_] = wt[(kk * 32 + ic) * 16 + oc_];
  }
  __syncthreads();
  const int oc = tid & 15;
  const int pos = bl * 16 + (tid >> 4);
  const int my = pos >> 6, mx = pos & 63;
  float a = bs[oc];
#pragma unroll
  for (int ay = 0; ay < 2; ++ay) {
    int iy = my + py - 1 + ay;
    if ((unsigned)iy >= 64u) continue;
#pragma unroll
    for (int ax = 0; ax < 2; ++ax) {
      int ix = mx + px - 1 + ax;
      if ((unsigned)ix >= 64u) continue;
      const float4* xp = (const float4*)(in + ((n * 64 + iy) * 64 + ix) * 32);
      const int tp = ay * 2 + ax;
#pragma unroll
      for (int i4 = 0; i4 < 8; ++i4) {
        float4 xv = xp[i4];
        a = fmaf(xv.x, wl[tp][i4 * 4 + 0][oc], a);
        a = fmaf(xv.y, wl[tp][i4 * 4 + 1][oc], a);
        a = fmaf(xv.z, wl[tp][i4 * 4 + 2][oc], a);
        a = fmaf(xv.w, wl[tp][i4 * 4 + 3][oc], a);
      }
    }
  }
  const int oy = 2 * my + py, ox = 2 * mx + px;
  out[((n * 128 + oy) * 128 + ox) * 16 + oc] = (a > 0.f) ? a : 0.2f * a;
}

__global__ __launch_bounds__(256) void dec_s3(const float* __restrict__ in,
                                              const float* __restrict__ wt,
                                              const float* __restrict__ bs,
                                              float* __restrict__ out) {
  int t = blockIdx.x * 256 + threadIdx.x;
  int ox = t & 127, oy = (t >> 7) & 127, n = t >> 14;
  float a = bs[0];
#pragma unroll
  for (int ky = 0; ky < 3; ++ky) {
    int iy = oy + ky - 1;
    if ((unsigned)iy >= 128u) continue;
#pragma unroll
    for (int kx = 0; kx < 3; ++kx) {
      int ix = ox + kx - 1;
      if ((unsigned)ix >= 128u) continue;
      const float4* xp = (const float4*)(in + ((n * 128 + iy) * 128 + ix) * 16);
      const float4* wp = (const float4*)(wt + (ky * 3 + kx) * 16);
#pragma unroll
      for (int i4 = 0; i4 < 4; ++i4) {
        float4 xv = xp[i4], wv = wp[i4];
        a = fmaf(xv.x, wv.x, a);
        a = fmaf(xv.y, wv.y, a);
        a = fmaf(xv.z, wv.z, a);
        a = fmaf(xv.w, wv.w, a);
      }
    }
  }
  out[n * 16384 + oy * 128 + ox] = a;
}

// ---------------- host ----------------
extern "C" void kernel_launch(void* const* d_in, const int* in_sizes, int n_in,
                              void* d_out, int out_size, void* d_ws, size_t ws_size,
                              hipStream_t stream) {
  (void)in_sizes; (void)n_in; (void)out_size; (void)ws_size;
  (void)hipFuncSetAttribute((const void*)ode_persist,
                            hipFuncAttributeMaxDynamicSharedMemorySize, CONV_LDS);

  uint8_t* ws = (uint8_t*)d_ws;
  uint32_t* S0 = (uint32_t*)(ws + 0);         // packed state, 1 MB each
  uint32_t* S1 = (uint32_t*)(ws + 1048576);
  uint32_t* T0 = (uint32_t*)(ws + 2097152);
  uint32_t* T1 = (uint32_t*)(ws + 3145728);
  unsigned short* WIMG = (unsigned short*)(ws + 4194304);   // 589824 B
  float* s1wt = (float*)(ws + 4784128);
  float* s2wt = (float*)(ws + 4915200);
  float* s3wt = (float*)(ws + 4947968);
  int* progress = (int*)(ws + 4980736);       // 64 x int
  float* outs = (float*)(ws + 5242880);       // 10 x 262144 f32
  float* d1 = (float*)(ws + 16777216);        // decoder scratch 2 MB
  float* d2 = (float*)(ws + 18874368);        // decoder scratch 4 MB

  const float* h_s0 = (const float*)d_in[0];
  const float* wode[4] = {(const float*)d_in[1], (const float*)d_in[3],
                          (const float*)d_in[5], (const float*)d_in[7]};
  const float* bode[4] = {(const float*)d_in[2], (const float*)d_in[4],
                          (const float*)d_in[6], (const float*)d_in[8]};
  const float* s1w = (const float*)d_in[9];
  const float* s1b = (const float*)d_in[10];
  const float* s2w = (const float*)d_in[11];
  const float* s2b = (const float*)d_in[12];
  const float* s3w = (const float*)d_in[13];
  const float* s3b = (const float*)d_in[14];

  (void)hipMemsetAsync(progress, 0, 64 * sizeof(int), stream);
  prep_weights<<<737, 256, 0, stream>>>(wode[0], wode[1], wode[2], wode[3],
                                        s1w, s2w, s3w, WIMG, s1wt, s2wt, s3wt);
  prep_state<<<1024, 256, 0, stream>>>(h_s0, S0, outs);

  ode_persist<<<dim3(64), dim3(1024), CONV_LDS, stream>>>(
      WIMG, bode[0], bode[1], bode[2], bode[3],
      S0, S1, T0, T1, outs, progress);

  for (int t0 = 0; t0 < 10; ++t0) {
    dec_s1<<<2048, 256, 0, stream>>>(outs + (size_t)t0 * 262144, s1wt, s1b, d1);
    dec_s2<<<4096, 256, 0, stream>>>(d1, s2wt, s2b, d2);
    dec_s3<<<256, 256, 0, stream>>>(d2, s3wt, s3b,
                                    (float*)d_out + (size_t)t0 * 65536);
  }
}

// Round 18
// 3537.695 us; speedup vs baseline: 1.9362x; 1.1820x over previous
//
#include <hip/hip_runtime.h>
#include <hip/hip_bf16.h>
#include <stdint.h>

typedef __attribute__((ext_vector_type(8))) short short8;
typedef __attribute__((ext_vector_type(4))) float f32x4;
typedef __attribute__((ext_vector_type(4))) int int4v;

__device__ __forceinline__ float bf2f(unsigned short u) {
  union { unsigned int i; float f; } v; v.i = ((unsigned int)u) << 16; return v.f;
}
__device__ __forceinline__ unsigned short f2bf(float f) {
  union { float f; unsigned int i; } v; v.f = f;
  unsigned int i = v.i;
  i += 0x7FFFu + ((i >> 16) & 1u);
  return (unsigned short)(i >> 16);
}
__device__ __forceinline__ float tanh_fast(float x) {
  float e = __expf(2.0f * x);
  return 1.0f - 2.0f / (e + 1.0f);
}
__device__ __forceinline__ uint32_t pack_pair(float v) {
  unsigned short hi = f2bf(v);
  unsigned short lo = f2bf(v - bf2f(hi));
  return (uint32_t)hi | ((uint32_t)lo << 16);
}

// ---------------- weight prep ----------------
// ODE: wimg[arr(hi/lo)][icb][oc][tap][icm] per layer (73728 elems/layer), bf16
// decoder (oc-contiguous): s1wt[kk][ic64][oc32], s2wt[kk][ic32][oc16], s3wt[kk][ic16]
__global__ void prep_weights(const float* __restrict__ w1, const float* __restrict__ w2,
                             const float* __restrict__ w3, const float* __restrict__ w4,
                             const float* __restrict__ s1w, const float* __restrict__ s2w,
                             const float* __restrict__ s3w,
                             unsigned short* __restrict__ wimg,
                             float* __restrict__ s1wt, float* __restrict__ s2wt,
                             float* __restrict__ s3wt) {
  int t = blockIdx.x * 256 + threadIdx.x;
  if (t < 147456) {
    int l = t / 36864;
    int oc = (t / 576) & 63;
    int ic = (t / 9) & 63;
    int tap = t % 9;
    const float* w = (l == 0) ? w1 : (l == 1) ? w2 : (l == 2) ? w3 : w4;
    float v = w[(oc * 64 + ic) * 9 + tap];
    unsigned short hi = f2bf(v);
    unsigned short lo = f2bf(v - bf2f(hi));
    int icb = ic >> 5, icm = ic & 31;
    int idx = (icb * 64 + oc) * 288 + tap * 32 + icm;
    wimg[l * 73728 + idx]         = hi;
    wimg[l * 73728 + 36864 + idx] = lo;
  } else if (t < 180224) {
    int u = t - 147456;                       // -> s1wt[(kk*64+ic)*32+oc]
    int oc = u & 31, ic = (u >> 5) & 63, kk = u >> 11;
    int ky = kk >> 2, kx = kk & 3;
    s1wt[(kk * 64 + ic) * 32 + oc] = s1w[((oc * 64 + ic) * 4 + ky) * 4 + kx];
  } else if (t < 188416) {
    int u = t - 180224;                       // -> s2wt[(kk*32+ic)*16+oc]
    int oc = u & 15, ic = (u >> 4) & 31, kk = u >> 9;
    int ky = kk >> 2, kx = kk & 3;
    s2wt[(kk * 32 + ic) * 16 + oc] = s2w[((oc * 32 + ic) * 4 + ky) * 4 + kx];
  } else if (t < 188560) {
    int u = t - 188416;                       // [kk][ic16]
    int ic = u & 15, kk = u >> 4;
    int ky = kk / 3, kx = kk % 3;
    s3wt[u] = s3w[ic * 9 + ky * 3 + kx];
  }
}

// NCHW h_s0 -> packed S0 + Yb f32 + outs[0]
__global__ void prep_state(const float* __restrict__ src,
                           uint32_t* __restrict__ s0, float* __restrict__ Yb,
                           float* __restrict__ outs0) {
  int t = blockIdx.x * 256 + threadIdx.x;    // NHWC flat: ((b*32+h)*32+w)*64+c
  int c = t & 63, w = (t >> 6) & 31, h = (t >> 11) & 31, b = t >> 16;
  float v = src[((b * 64 + c) * 32 + h) * 32 + w];
  s0[t] = pack_pair(v);
  Yb[t] = v;
  outs0[t] = v;
}

// ---------------- ODE conv body: 512 thr, 8 waves = kq2 x (mt2 x nt2) ---------
// Wave tile M32 (row h0+mt) x N32 (oc nt*32..+31) = 2x2 quadrants of 16x16x32.
// K-split-2 over 18 (icb,tap) slices: phase icb0 {kq0: taps 0-4, kq1: 5-8},
// phase icb1 {kq0: taps 0-3, kq1: 4-8} -> 9 slices per kq.
// LDS: A[2 buf][arr2][pix136][chunk8]x16B (XOR swizzle)  -> 69632 B
//      W[arr2][oc64][slot40]x16B, one icb, re-staged mid-conv -> 81920 B
// K-reduction scratch (16 KB) lives in An rows 0 & 3 (fully re-staged next conv).
// State handoff: packed uint32, relaxed agent atomics (IC), NO fences.
// Y/R: block-private global f32 (L1-hot), touched only on layer-4 convs.
#define A_BUF 34816
#define A_ARR 17408
#define WBASE 69632
#define W_ARR 40960
#define CONV_LDS 151552

__device__ __forceinline__ int red_off(int tl, int lane, int q) {
  int ridx = (((tl << 6) + lane) * 4 + q) * 16;   // 0..16368
  int seg = ridx >> 12;                            // 4 KB segments
  return (seg & 1) * 13056 + (seg >> 1) * A_ARR + (ridx & 4095);
}

__device__ __forceinline__ void slice_run(
    const uint8_t* lds, const uint8_t* A, int tap, int icb,
    int mt, int lmod, int lg, int oc0,
    f32x4& a00, f32x4& a01, f32x4& a10, f32x4& a11) {
  const int dy = tap / 3, dx = tap % 3;
  const int slot = tap * 4 + lg;
  const int oc1 = oc0 + 16;
  const int wb0 = WBASE + oc0 * 640 + ((slot ^ (oc0 & 7)) * 16);
  const int wb1 = WBASE + oc1 * 640 + ((slot ^ (oc1 & 7)) * 16);
  short8 bh0 = *(const short8*)(lds + wb0);
  short8 bh1 = *(const short8*)(lds + wb1);
  short8 bl0 = *(const short8*)(lds + wb0 + W_ARR);
  short8 bl1 = *(const short8*)(lds + wb1 + W_ARR);
  const int chunk = icb * 4 + lg;
  const int pix0 = (mt + dy) * 34 + (lmod + dx);
  const int pix1 = pix0 + 16;
  const int ab0 = pix0 * 128 + ((chunk ^ (pix0 & 7)) * 16);
  const int ab1 = pix1 * 128 + ((chunk ^ (pix1 & 7)) * 16);
  short8 ah0 = *(const short8*)(A + ab0);
  short8 al0 = *(const short8*)(A + A_ARR + ab0);
  short8 ah1 = *(const short8*)(A + ab1);
  short8 al1 = *(const short8*)(A + A_ARR + ab1);
  a00 = __builtin_amdgcn_mfma_f32_16x16x32_bf16(ah0, bh0, a00, 0, 0, 0);
  a00 = __builtin_amdgcn_mfma_f32_16x16x32_bf16(al0, bh0, a00, 0, 0, 0);
  a00 = __builtin_amdgcn_mfma_f32_16x16x32_bf16(ah0, bl0, a00, 0, 0, 0);
  a01 = __builtin_amdgcn_mfma_f32_16x16x32_bf16(ah0, bh1, a01, 0, 0, 0);
  a01 = __builtin_amdgcn_mfma_f32_16x16x32_bf16(al0, bh1, a01, 0, 0, 0);
  a01 = __builtin_amdgcn_mfma_f32_16x16x32_bf16(ah0, bl1, a01, 0, 0, 0);
  a10 = __builtin_amdgcn_mfma_f32_16x16x32_bf16(ah1, bh0, a10, 0, 0, 0);
  a10 = __builtin_amdgcn_mfma_f32_16x16x32_bf16(al1, bh0, a10, 0, 0, 0);
  a10 = __builtin_amdgcn_mfma_f32_16x16x32_bf16(ah1, bl0, a10, 0, 0, 0);
  a11 = __builtin_amdgcn_mfma_f32_16x16x32_bf16(ah1, bh1, a11, 0, 0, 0);
  a11 = __builtin_amdgcn_mfma_f32_16x16x32_bf16(al1, bh1, a11, 0, 0, 0);
  a11 = __builtin_amdgcn_mfma_f32_16x16x32_bf16(ah1, bl1, a11, 0, 0, 0);
}

__device__ __forceinline__ void stage_w(uint8_t* lds,
                                        const unsigned short* __restrict__ wimgL,
                                        int tid, int p) {
#pragma unroll
  for (int k = 0; k < 9; ++k) {
    int idx = tid + k * 512;                  // 0..4607
    int arr = idx / 2304;
    int r2 = idx - arr * 2304;
    int oc = r2 / 36;
    int ch = r2 - oc * 36;
    int4v v = *(const int4v*)(wimgL + (((arr * 2 + p) * 64 + oc) * 288 + ch * 8));
    *(int4v*)(lds + WBASE + arr * W_ARR + oc * 640 + ((ch ^ (oc & 7)) * 16)) = v;
  }
}

__device__ __forceinline__ void conv_body(
    uint8_t* lds, int b, int h0, int cur, int full,
    const uint32_t* __restrict__ inP,
    const unsigned short* __restrict__ wimgL, const float* __restrict__ bias,
    uint32_t* __restrict__ outP, float* __restrict__ Yb, float* __restrict__ Rb,
    float* __restrict__ op, int mode) {
  const int tid = threadIdx.x;
  uint8_t* A = lds + cur * A_BUF;
  uint8_t* An = lds + (cur ^ 1) * A_BUF;

  // ---- stage A rows from IC: full (4 rows, first conv) or halo rows {0,3}
  const int nitems = full ? 1088 : 544;
  for (int idx = tid; idx < nitems; idx += 512) {
    int c = idx & 7;
    int w1 = (idx >> 3) % 34;
    int rsel = (idx >> 3) / 34;
    int row = full ? rsel : rsel * 3;         // halo: rows 0 and 3
    int hp = h0 - 1 + row;
    int w = w1 - 1;
    short8 hi8 = {0, 0, 0, 0, 0, 0, 0, 0};
    short8 lo8 = {0, 0, 0, 0, 0, 0, 0, 0};
    if (hp >= 0 && hp < 32 && w >= 0 && w < 32) {
      const uint64_t* sp = (const uint64_t*)(inP + (((b * 32 + hp) * 32 + w) * 64 + c * 8));
#pragma unroll
      for (int q = 0; q < 4; ++q) {
        uint64_t pk2 = __hip_atomic_load(sp + q, __ATOMIC_RELAXED,
                                         __HIP_MEMORY_SCOPE_AGENT);
        uint32_t p0 = (uint32_t)pk2, p1 = (uint32_t)(pk2 >> 32);
        hi8[q * 2]     = (short)(p0 & 0xFFFFu);
        lo8[q * 2]     = (short)(p0 >> 16);
        hi8[q * 2 + 1] = (short)(p1 & 0xFFFFu);
        lo8[q * 2 + 1] = (short)(p1 >> 16);
      }
    }
    const int pix = row * 34 + w1;
    const int off = pix * 128 + ((c ^ (pix & 7)) * 16);
    *(short8*)(A + off) = hi8;
    *(short8*)(A + A_ARR + off) = lo8;
  }
  stage_w(lds, wimgL, tid, 0);
  __syncthreads();                            // b1: A + W(icb0) ready

  const int lane = tid & 63;
  const int wv = tid >> 6;                    // 0..7
  const int kq = wv >> 2;                     // 0..1
  const int tl = wv & 3;
  const int mt = tl >> 1, nt = tl & 1;
  const int lmod = lane & 15, lg = lane >> 4;
  const int oc0 = nt * 32 + lmod;

  f32x4 a00 = {0.f,0.f,0.f,0.f}, a01 = {0.f,0.f,0.f,0.f};
  f32x4 a10 = {0.f,0.f,0.f,0.f}, a11 = {0.f,0.f,0.f,0.f};

  // ---- phase 0 (icb0): kq0 taps 0-4, kq1 taps 5-8
  if (kq == 0) {
#pragma unroll
    for (int t = 0; t < 5; ++t)
      slice_run(lds, A, t, 0, mt, lmod, lg, oc0, a00, a01, a10, a11);
  } else {
#pragma unroll
    for (int t = 5; t < 9; ++t)
      slice_run(lds, A, t, 0, mt, lmod, lg, oc0, a00, a01, a10, a11);
  }
  __syncthreads();                            // b2: W region free
  stage_w(lds, wimgL, tid, 1);
  __syncthreads();                            // b3: W(icb1) ready
  // ---- phase 1 (icb1): kq0 taps 0-3, kq1 taps 4-8
  if (kq == 0) {
#pragma unroll
    for (int t = 0; t < 4; ++t)
      slice_run(lds, A, t, 1, mt, lmod, lg, oc0, a00, a01, a10, a11);
  } else {
#pragma unroll
    for (int t = 4; t < 9; ++t)
      slice_run(lds, A, t, 1, mt, lmod, lg, oc0, a00, a01, a10, a11);
  }

  // ---- K-reduction via An rows 0&3 scratch (re-staged next conv)
  if (kq == 1) {
    *(f32x4*)(An + red_off(tl, lane, 0)) = a00;
    *(f32x4*)(An + red_off(tl, lane, 1)) = a01;
    *(f32x4*)(An + red_off(tl, lane, 2)) = a10;
    *(f32x4*)(An + red_off(tl, lane, 3)) = a11;
  }
  __syncthreads();                            // b4: partials visible

  if (kq == 0) {
    a00 += *(const f32x4*)(An + red_off(tl, lane, 0));
    a01 += *(const f32x4*)(An + red_off(tl, lane, 1));
    a10 += *(const f32x4*)(An + red_off(tl, lane, 2));
    a11 += *(const f32x4*)(An + red_off(tl, lane, 3));
    // ---- epilogue: quadrant q=(msub,nsub); px = mt*32 + msub*16 + lg*4 + j
#pragma unroll
    for (int msub = 0; msub < 2; ++msub) {
#pragma unroll
      for (int nsub = 0; nsub < 2; ++nsub) {
        const int q = msub * 2 + nsub;
        f32x4 accv = (q == 0) ? a00 : (q == 1) ? a01 : (q == 2) ? a10 : a11;
        const int oc = nt * 32 + nsub * 16 + lmod;
        const float bz = bias[oc];
#pragma unroll
        for (int j = 0; j < 4; ++j) {
          const int px = mt * 32 + msub * 16 + lg * 4 + j;
          const int e = (b * 1024 + h0 * 32 + px) * 64 + oc;
          float kv = accv[j] + bz;
          float z;
          if (mode == 0) {                    // conv + tanh
            z = tanh_fast(kv);
          } else if (mode == 1) {             // k1: z=y+0.25k ; R=y+k/12
            float y = Yb[e];
            z = fmaf(0.25f, kv, y);
            Rb[e] = fmaf(1.0f / 12.0f, kv, y);
          } else if (mode == 2 || mode == 3) { // k2/k3
            float y = Yb[e];
            float cz = (mode == 2) ? 0.25f : 0.5f;
            z = fmaf(cz, kv, y);
            Rb[e] = fmaf(1.0f / 6.0f, kv, Rb[e]);
          } else {                            // k4: ynew = R + k/12
            z = fmaf(1.0f / 12.0f, kv, Rb[e]);
            Yb[e] = z;
            if (op) op[e] = z;
          }
          uint32_t pk = pack_pair(z);
          __hip_atomic_store(&outP[e], pk, __ATOMIC_RELAXED,
                             __HIP_MEMORY_SCOPE_AGENT);
          // own rows into A[next]: tile row = 1 + mt, w1 = (px&31)+1
          const int pix = (1 + (px >> 5)) * 34 + (px & 31) + 1;
          const int off = pix * 128 + (((oc >> 3) ^ (pix & 7)) * 16) + (oc & 7) * 2;
          *(unsigned short*)(An + off)         = (unsigned short)(pk & 0xFFFFu);
          *(unsigned short*)(An + A_ARR + off) = (unsigned short)(pk >> 16);
        }
      }
    }
  }
}

// ---------------- persistent ODE kernel: 64 blocks x 8 waves, neighbor-sync ---
__global__ __launch_bounds__(512) void ode_persist(
    const unsigned short* __restrict__ wimg,
    const float* __restrict__ b1, const float* __restrict__ b2,
    const float* __restrict__ b3, const float* __restrict__ b4,
    uint32_t* __restrict__ S0, uint32_t* __restrict__ S1,
    uint32_t* __restrict__ T0, uint32_t* __restrict__ T1,
    float* __restrict__ Yb, float* __restrict__ Rb,
    float* __restrict__ outs, int* progress) {
  extern __shared__ uint8_t lds[];
  const int blk = blockIdx.x;
  const int b = blk >> 4;
  const int rp = blk & 15;
  const int h0 = rp << 1;
  const int nbA = (rp > 0) ? blk - 1 : -1;
  const int nbB = (rp < 15) ? blk + 1 : -1;

  const unsigned short* Wl[4] = {wimg, wimg + 73728, wimg + 147456, wimg + 221184};
  const float* Bl[4] = {b1, b2, b3, b4};

  // zero pad columns (w1 = 0, 33) of epilogue-written rows 1,2 in BOTH A bufs
  if (threadIdx.x < 128) {
    int t = threadIdx.x;
    int chunk = t & 7;
    int col = ((t >> 3) & 1) * 33;
    int row = 1 + ((t >> 4) & 1);
    int arr = (t >> 5) & 1;
    int buf = (t >> 6) & 1;
    int pix = row * 34 + col;
    *(int4v*)(lds + buf * A_BUF + arr * A_ARR + pix * 128 +
              ((chunk ^ (pix & 7)) * 16)) = (int4v){0, 0, 0, 0};
  }
  __syncthreads();

  int done = 0;
  int cur = 0;
  for (int step = 1; step <= 18; ++step) {
    for (int sub = 0; sub < 4; ++sub) {
      for (int layer = 0; layer < 4; ++layer) {
        const uint32_t* inP;
        uint32_t* outP;
        int mode;
        float* op = nullptr;
        if (layer == 0) {
          inP = (sub == 0) ? S0 : S1; outP = T0; mode = 0;
        } else if (layer == 1) {
          inP = T0; outP = T1; mode = 0;
        } else if (layer == 2) {
          inP = T1; outP = T0; mode = 0;
        } else {
          inP = T0; outP = (sub == 3) ? S0 : S1; mode = 1 + sub;
          if (sub == 3 && (step & 1) == 0) op = outs + (size_t)(step >> 1) * 262144;
        }
        if (threadIdx.x == 0 && done > 0) {
          if (nbA >= 0)
            while (__hip_atomic_load(&progress[nbA], __ATOMIC_RELAXED,
                                     __HIP_MEMORY_SCOPE_AGENT) < done)
              __builtin_amdgcn_s_sleep(2);
          if (nbB >= 0)
            while (__hip_atomic_load(&progress[nbB], __ATOMIC_RELAXED,
                                     __HIP_MEMORY_SCOPE_AGENT) < done)
              __builtin_amdgcn_s_sleep(2);
        }
        __builtin_amdgcn_sched_barrier(0);
        __syncthreads();

        conv_body(lds, b, h0, cur, done == 0, inP, Wl[layer], Bl[layer], outP,
                  Yb, Rb, op, mode);

        __syncthreads();                      // drains all waves' stores (vmcnt)
        ++done;
        cur ^= 1;
        if (threadIdx.x == 0) {
          __hip_atomic_store(&progress[blk], done, __ATOMIC_RELEASE,
                             __HIP_MEMORY_SCOPE_AGENT);
        }
      }
    }
  }
}

// ---------------- decoder: parity-specialized blocks, LDS weights -------------
__global__ __launch_bounds__(256) void dec_s1(const float* __restrict__ in,
                                              const float* __restrict__ wt,
                                              const float* __restrict__ bs,
                                              float* __restrict__ out) {
  __shared__ float wl[4][64][32];
  const int tid = threadIdx.x;
  const int bl = blockIdx.x & 127;
  const int par = (blockIdx.x >> 7) & 3;
  const int n = blockIdx.x >> 9;
  const int py = par >> 1, px = par & 1;
#pragma unroll
  for (int k = 0; k < 32; ++k) {
    int s = tid + k * 256;                    // 0..8191
    int oc_ = s & 31, ic = (s >> 5) & 63, tp = s >> 11;
    int kk = (py + 2 * (tp >> 1)) * 4 + (px + 2 * (tp & 1));
    wl[tp][ic][oc_] = wt[(kk * 64 + ic) * 32 + oc_];
  }
  __syncthreads();
  const int oc = tid & 31;
  const int pos = bl * 8 + (tid >> 5);
  const int my = pos >> 5, mx = pos & 31;
  float a = bs[oc];
#pragma unroll
  for (int ay = 0; ay < 2; ++ay) {
    int iy = my + py - 1 + ay;
    if ((unsigned)iy >= 32u) continue;
#pragma unroll
    for (int ax = 0; ax < 2; ++ax) {
      int ix = mx + px - 1 + ax;
      if ((unsigned)ix >= 32u) continue;
      const float4* xp = (const float4*)(in + ((n * 32 + iy) * 32 + ix) * 64);
      const int tp = ay * 2 + ax;
#pragma unroll
      for (int i4 = 0; i4 < 16; ++i4) {
        float4 xv = xp[i4];
        a = fmaf(xv.x, wl[tp][i4 * 4 + 0][oc], a);
        a = fmaf(xv.y, wl[tp][i4 * 4 + 1][oc], a);
        a = fmaf(xv.z, wl[tp][i4 * 4 + 2][oc], a);
        a = fmaf(xv.w, wl[tp][i4 * 4 + 3][oc], a);
      }
    }
  }
  const int oy = 2 * my + py, ox = 2 * mx + px;
  out[((n * 64 + oy) * 64 + ox) * 32 + oc] = (a > 0.f) ? a : 0.2f * a;
}

__global__ __launch_bounds__(256) void dec_s2(const float* __restrict__ in,
                                              const float* __restrict__ wt,
                                              const float* __restrict__ bs,
                                              float* __restrict__ out) {
  __shared__ float wl[4][32][16];
  const int tid = threadIdx.x;
  const int bl = blockIdx.x & 255;
  const int par = (blockIdx.x >> 8) & 3;
  const int n = blockIdx.x >> 10;
  const int py = par >> 1, px = par & 1;
#pragma unroll
  for (int k = 0; k < 8; ++k) {
    int s = tid + k * 256;                    // 0..2047
    int oc_ = s & 15, ic = (s >> 4) & 31, tp = s >> 9;
    int kk = (py + 2 * (tp >> 1)) * 4 + (px + 2 * (tp & 1));
    wl[tp][ic][oc_] = wt[(kk * 32 + ic) * 16 + oc_];
  }
  __syncthreads();
  const int oc = tid & 15;
  const int pos = bl * 16 + (tid >> 4);
  const int my = pos >> 6, mx = pos & 63;
  float a = bs[oc];
#pragma unroll
  for (int ay = 0; ay < 2; ++ay) {
    int iy = my + py - 1 + ay;
    if ((unsigned)iy >= 64u) continue;
#pragma unroll
    for (int ax = 0; ax < 2; ++ax) {
      int ix = mx + px - 1 + ax;
      if ((unsigned)ix >= 64u) continue;
      const float4* xp = (const float4*)(in + ((n * 64 + iy) * 64 + ix) * 32);
      const int tp = ay * 2 + ax;
#pragma unroll
      for (int i4 = 0; i4 < 8; ++i4) {
        float4 xv = xp[i4];
        a = fmaf(xv.x, wl[tp][i4 * 4 + 0][oc], a);
        a = fmaf(xv.y, wl[tp][i4 * 4 + 1][oc], a);
        a = fmaf(xv.z, wl[tp][i4 * 4 + 2][oc], a);
        a = fmaf(xv.w, wl[tp][i4 * 4 + 3][oc], a);
      }
    }
  }
  const int oy = 2 * my + py, ox = 2 * mx + px;
  out[((n * 128 + oy) * 128 + ox) * 16 + oc] = (a > 0.f) ? a : 0.2f * a;
}

__global__ __launch_bounds__(256) void dec_s3(const float* __restrict__ in,
                                              const float* __restrict__ wt,
                                              const float* __restrict__ bs,
                                              float* __restrict__ out) {
  int t = blockIdx.x * 256 + threadIdx.x;
  int ox = t & 127, oy = (t >> 7) & 127, n = t >> 14;
  float a = bs[0];
#pragma unroll
  for (int ky = 0; ky < 3; ++ky) {
    int iy = oy + ky - 1;
    if ((unsigned)iy >= 128u) continue;
#pragma unroll
    for (int kx = 0; kx < 3; ++kx) {
      int ix = ox + kx - 1;
      if ((unsigned)ix >= 128u) continue;
      const float4* xp = (const float4*)(in + ((n * 128 + iy) * 128 + ix) * 16);
      const float4* wp = (const float4*)(wt + (ky * 3 + kx) * 16);
#pragma unroll
      for (int i4 = 0; i4 < 4; ++i4) {
        float4 xv = xp[i4], wv = wp[i4];
        a = fmaf(xv.x, wv.x, a);
        a = fmaf(xv.y, wv.y, a);
        a = fmaf(xv.z, wv.z, a);
        a = fmaf(xv.w, wv.w, a);
      }
    }
  }
  out[n * 16384 + oy * 128 + ox] = a;
}

// ---------------- host ----------------
extern "C" void kernel_launch(void* const* d_in, const int* in_sizes, int n_in,
                              void* d_out, int out_size, void* d_ws, size_t ws_size,
                              hipStream_t stream) {
  (void)in_sizes; (void)n_in; (void)out_size; (void)ws_size;
  (void)hipFuncSetAttribute((const void*)ode_persist,
                            hipFuncAttributeMaxDynamicSharedMemorySize, CONV_LDS);

  uint8_t* ws = (uint8_t*)d_ws;
  uint32_t* S0 = (uint32_t*)(ws + 0);         // packed state, 1 MB each
  uint32_t* S1 = (uint32_t*)(ws + 1048576);
  uint32_t* T0 = (uint32_t*)(ws + 2097152);
  uint32_t* T1 = (uint32_t*)(ws + 3145728);
  float* Yb = (float*)(ws + 4194304);         // 1 MB
  float* Rb = (float*)(ws + 5242880);         // 1 MB
  unsigned short* WIMG = (unsigned short*)(ws + 6291456);   // 589824 B
  float* s1wt = (float*)(ws + 6881280);
  float* s2wt = (float*)(ws + 7012352);
  float* s3wt = (float*)(ws + 7045120);
  int* progress = (int*)(ws + 7077888);       // 64 x int
  float* outs = (float*)(ws + 7340032);       // 10 x 262144 f32
  float* d1 = (float*)(ws + 0);               // decoder scratch (ODE bufs dead)
  float* d2 = (float*)(ws + 2097152);

  const float* h_s0 = (const float*)d_in[0];
  const float* wode[4] = {(const float*)d_in[1], (const float*)d_in[3],
                          (const float*)d_in[5], (const float*)d_in[7]};
  const float* bode[4] = {(const float*)d_in[2], (const float*)d_in[4],
                          (const float*)d_in[6], (const float*)d_in[8]};
  const float* s1w = (const float*)d_in[9];
  const float* s1b = (const float*)d_in[10];
  const float* s2w = (const float*)d_in[11];
  const float* s2b = (const float*)d_in[12];
  const float* s3w = (const float*)d_in[13];
  const float* s3b = (const float*)d_in[14];

  (void)hipMemsetAsync(progress, 0, 64 * sizeof(int), stream);
  prep_weights<<<737, 256, 0, stream>>>(wode[0], wode[1], wode[2], wode[3],
                                        s1w, s2w, s3w, WIMG, s1wt, s2wt, s3wt);
  prep_state<<<1024, 256, 0, stream>>>(h_s0, S0, Yb, outs);

  ode_persist<<<dim3(64), dim3(512), CONV_LDS, stream>>>(
      WIMG, bode[0], bode[1], bode[2], bode[3],
      S0, S1, T0, T1, Yb, Rb, outs, progress);

  for (int t0 = 0; t0 < 10; ++t0) {
    dec_s1<<<2048, 256, 0, stream>>>(outs + (size_t)t0 * 262144, s1wt, s1b, d1);
    dec_s2<<<4096, 256, 0, stream>>>(d1, s2wt, s2b, d2);
    dec_s3<<<256, 256, 0, stream>>>(d2, s3wt, s3b,
                                    (float*)d_out + (size_t)t0 * 65536);
  }
}

// Round 19
// 2674.850 us; speedup vs baseline: 2.5608x; 1.3226x over previous
//
#include <hip/hip_runtime.h>
#include <hip/hip_bf16.h>
#include <stdint.h>

typedef __attribute__((ext_vector_type(8))) short short8;
typedef __attribute__((ext_vector_type(4))) float f32x4;
typedef __attribute__((ext_vector_type(4))) int int4v;

__device__ __forceinline__ float bf2f(unsigned short u) {
  union { unsigned int i; float f; } v; v.i = ((unsigned int)u) << 16; return v.f;
}
__device__ __forceinline__ unsigned short f2bf(float f) {
  union { float f; unsigned int i; } v; v.f = f;
  unsigned int i = v.i;
  i += 0x7FFFu + ((i >> 16) & 1u);
  return (unsigned short)(i >> 16);
}
__device__ __forceinline__ float tanh_fast(float x) {
  float e = __expf(2.0f * x);
  return 1.0f - 2.0f / (e + 1.0f);
}
__device__ __forceinline__ uint32_t pack_pair(float v) {
  unsigned short hi = f2bf(v);
  unsigned short lo = f2bf(v - bf2f(hi));
  return (uint32_t)hi | ((uint32_t)lo << 16);
}

// ---------------- weight prep ----------------
// ODE: wimg[arr(hi/lo)][icb][oc][tap][icm] per layer (73728 elems/layer), bf16
// decoder (oc-contiguous): s1wt[kk][ic64][oc32], s2wt[kk][ic32][oc16], s3wt[kk][ic16]
__global__ void prep_weights(const float* __restrict__ w1, const float* __restrict__ w2,
                             const float* __restrict__ w3, const float* __restrict__ w4,
                             const float* __restrict__ s1w, const float* __restrict__ s2w,
                             const float* __restrict__ s3w,
                             unsigned short* __restrict__ wimg,
                             float* __restrict__ s1wt, float* __restrict__ s2wt,
                             float* __restrict__ s3wt) {
  int t = blockIdx.x * 256 + threadIdx.x;
  if (t < 147456) {
    int l = t / 36864;
    int oc = (t / 576) & 63;
    int ic = (t / 9) & 63;
    int tap = t % 9;
    const float* w = (l == 0) ? w1 : (l == 1) ? w2 : (l == 2) ? w3 : w4;
    float v = w[(oc * 64 + ic) * 9 + tap];
    unsigned short hi = f2bf(v);
    unsigned short lo = f2bf(v - bf2f(hi));
    int icb = ic >> 5, icm = ic & 31;
    int idx = (icb * 64 + oc) * 288 + tap * 32 + icm;
    wimg[l * 73728 + idx]         = hi;
    wimg[l * 73728 + 36864 + idx] = lo;
  } else if (t < 180224) {
    int u = t - 147456;                       // -> s1wt[(kk*64+ic)*32+oc]
    int oc = u & 31, ic = (u >> 5) & 63, kk = u >> 11;
    int ky = kk >> 2, kx = kk & 3;
    s1wt[(kk * 64 + ic) * 32 + oc] = s1w[((oc * 64 + ic) * 4 + ky) * 4 + kx];
  } else if (t < 188416) {
    int u = t - 180224;                       // -> s2wt[(kk*32+ic)*16+oc]
    int oc = u & 15, ic = (u >> 4) & 31, kk = u >> 9;
    int ky = kk >> 2, kx = kk & 3;
    s2wt[(kk * 32 + ic) * 16 + oc] = s2w[((oc * 32 + ic) * 4 + ky) * 4 + kx];
  } else if (t < 188560) {
    int u = t - 188416;                       // [kk][ic16]
    int ic = u & 15, kk = u >> 4;
    int ky = kk / 3, kx = kk % 3;
    s3wt[u] = s3w[ic * 9 + ky * 3 + kx];
  }
}

// NCHW h_s0 -> packed S0 + f32 outs[0]
__global__ void prep_state(const float* __restrict__ src,
                           uint32_t* __restrict__ s0, float* __restrict__ outs0) {
  int t = blockIdx.x * 256 + threadIdx.x;    // NHWC flat: ((b*32+h)*32+w)*64+c
  int c = t & 63, w = (t >> 6) & 31, h = (t >> 11) & 31, b = t >> 16;
  float v = src[((b * 64 + c) * 32 + h) * 32 + w];
  s0[t] = pack_pair(v);
  outs0[t] = v;
}

// ---------------- ODE conv body (1024 thr, 16 waves; wave = M16 x N16) --------
// LDS (XOR-swizzled, bank-conflict-free):
//   A[2 buf][arr2][pix136][chunk8]x16B : entry = buf*34816 + arr*17408 +
//       pix*128 + ((chunk ^ (pix&7))*16)            -> 69632 B
//   W[arr2][oc64][slot40]x16B          : entry = WBASE + arr*40960 +
//       oc*640 + ((slot ^ (oc&7))*16), slot = tap*4+icpart  -> 81920 B
// State handoff: packed uint32, relaxed agent atomics (IC), NO fences.
// Own output rows are written into A[next] in LDS at epilogue; only the 2
// halo rows are staged from IC each conv.
#define A_BUF 34816
#define A_ARR 17408
#define WBASE 69632
#define W_ARR 40960
#define CONV_LDS 151552

__device__ __forceinline__ void conv_body(
    uint8_t* lds, int b, int h0, int cur, int full,
    const uint32_t* __restrict__ inP,
    const unsigned short* __restrict__ wimg, const float* __restrict__ bias,
    uint32_t* __restrict__ outP,
    float* Y, float* R, float* __restrict__ outsPtr, int mode) {
  const int tid = threadIdx.x;
  uint8_t* A = lds + cur * A_BUF;
  uint8_t* An = lds + (cur ^ 1) * A_BUF;

  // ---- stage A rows from IC: full (4 rows, first conv) or halo rows {0,3}
  const int nitems = full ? 1088 : 544;
  for (int idx = tid; idx < nitems; idx += 1024) {
    int c = idx & 7;
    int w1 = (idx >> 3) % 34;
    int rsel = (idx >> 3) / 34;
    int row = full ? rsel : rsel * 3;         // halo: rows 0 and 3
    int hp = h0 - 1 + row;
    int w = w1 - 1;
    short8 hi8 = {0, 0, 0, 0, 0, 0, 0, 0};
    short8 lo8 = {0, 0, 0, 0, 0, 0, 0, 0};
    if (hp >= 0 && hp < 32 && w >= 0 && w < 32) {
      const uint64_t* sp = (const uint64_t*)(inP + (((b * 32 + hp) * 32 + w) * 64 + c * 8));
#pragma unroll
      for (int q = 0; q < 4; ++q) {
        uint64_t pk2 = __hip_atomic_load(sp + q, __ATOMIC_RELAXED,
                                         __HIP_MEMORY_SCOPE_AGENT);
        uint32_t p0 = (uint32_t)pk2, p1 = (uint32_t)(pk2 >> 32);
        hi8[q * 2]     = (short)(p0 & 0xFFFFu);
        lo8[q * 2]     = (short)(p0 >> 16);
        hi8[q * 2 + 1] = (short)(p1 & 0xFFFFu);
        lo8[q * 2 + 1] = (short)(p1 >> 16);
      }
    }
    const int pix = row * 34 + w1;
    const int off = pix * 128 + ((c ^ (pix & 7)) * 16);
    *(short8*)(A + off) = hi8;
    *(short8*)(A + A_ARR + off) = lo8;
  }
  // ---- stage W icb=0 ; prefetch icb=1 into regs (write after phase-0 compute)
  int4v wpre[5];
#pragma unroll
  for (int k = 0; k < 5; ++k) {
    int idx = tid + k * 1024;                 // 0..4607
    if (idx < 4608) {
      int arr = idx / 2304;
      int r2 = idx - arr * 2304;
      int oc = r2 / 36;
      int ch = r2 - oc * 36;
      int4v v0 = *(const int4v*)(wimg + (((arr * 2 + 0) * 64 + oc) * 288 + ch * 8));
      *(int4v*)(lds + WBASE + arr * W_ARR + oc * 640 + ((ch ^ (oc & 7)) * 16)) = v0;
      wpre[k] = *(const int4v*)(wimg + (((arr * 2 + 1) * 64 + oc) * 288 + ch * 8));
    }
  }
  __syncthreads();

  const int lane = tid & 63;
  const int wv = tid >> 6;                    // 0..15
  const int mq = wv & 3;                      // M16 quarter
  const int ng = wv >> 2;                     // N16 group
  const int lmod = lane & 15;
  const int lg = lane >> 4;
  const int P = mq * 16 + lmod;               // A pixel (m = lane&15)
  const int r = P >> 5;
  const int c0 = P & 31;
  const int oc = ng * 16 + lmod;

  f32x4 acc = (f32x4){0.f, 0.f, 0.f, 0.f};

#pragma unroll
  for (int icb = 0; icb < 2; ++icb) {
    if (icb == 1) {
      __syncthreads();
#pragma unroll
      for (int k = 0; k < 5; ++k) {
        int idx = tid + k * 1024;
        if (idx < 4608) {
          int arr = idx / 2304;
          int r2 = idx - arr * 2304;
          int oco = r2 / 36;
          int ch = r2 - oco * 36;
          *(int4v*)(lds + WBASE + arr * W_ARR + oco * 640 + ((ch ^ (oco & 7)) * 16)) = wpre[k];
        }
      }
      __syncthreads();
    }
#pragma unroll
    for (int tap = 0; tap < 9; ++tap) {
      const int dy = tap / 3, dx = tap % 3;
      const int pix = (r + dy) * 34 + (c0 + dx);
      const int chunk = icb * 4 + lg;
      const int abyte = pix * 128 + ((chunk ^ (pix & 7)) * 16);
      short8 ah = *(const short8*)(A + abyte);
      short8 al = *(const short8*)(A + A_ARR + abyte);
      const int slot = tap * 4 + lg;
      const int wb = WBASE + oc * 640 + ((slot ^ (oc & 7)) * 16);
      short8 bh = *(const short8*)(lds + wb);
      short8 bl = *(const short8*)(lds + wb + W_ARR);
      acc = __builtin_amdgcn_mfma_f32_16x16x32_bf16(ah, bh, acc, 0, 0, 0);
      acc = __builtin_amdgcn_mfma_f32_16x16x32_bf16(al, bh, acc, 0, 0, 0);
      acc = __builtin_amdgcn_mfma_f32_16x16x32_bf16(ah, bl, acc, 0, 0, 0);
    }
  }

  // ---- epilogue: D[m=(lane>>4)*4+j][n=lane&15]; px = mq*16+m, oc = ng*16+n
  //      write z: packed -> global (for neighbor halo) AND own rows -> A[next]
  const float bz = bias[oc];
#pragma unroll
  for (int j = 0; j < 4; ++j) {
    const int px = mq * 16 + lg * 4 + j;
    const int e = (b * 1024 + h0 * 32 + px) * 64 + oc;
    float kv = acc[j] + bz;
    float z;
    if (mode == 0) {                          // conv + tanh
      z = tanh_fast(kv);
    } else if (mode == 1) {                   // k1: z=y+0.25k ; R=y+k/12
      z = fmaf(0.25f, kv, Y[j]);
      R[j] = fmaf(1.0f / 12.0f, kv, Y[j]);
    } else if (mode == 2 || mode == 3) {      // k2/k3
      float cz = (mode == 2) ? 0.25f : 0.5f;
      z = fmaf(cz, kv, Y[j]);
      R[j] = fmaf(1.0f / 6.0f, kv, R[j]);
    } else {                                  // k4: ynew = R + k/12
      z = fmaf(1.0f / 12.0f, kv, R[j]);
      Y[j] = z;
      if (outsPtr) outsPtr[e] = z;
    }
    uint32_t pk = pack_pair(z);
    __hip_atomic_store(&outP[e], pk, __ATOMIC_RELAXED, __HIP_MEMORY_SCOPE_AGENT);
    // own rows into A[next]: tile row = 1 + (px>>5), w1 = (px&31)+1
    const int pix = (1 + (px >> 5)) * 34 + (px & 31) + 1;
    const int off = pix * 128 + (((oc >> 3) ^ (pix & 7)) * 16) + (oc & 7) * 2;
    *(unsigned short*)(An + off)         = (unsigned short)(pk & 0xFFFFu);
    *(unsigned short*)(An + A_ARR + off) = (unsigned short)(pk >> 16);
  }
}

// ---------------- persistent ODE kernel: 64 blocks x 16 waves, neighbor-sync ---
// grid 64 = 4 batch x 16 row-pairs; 1 block/CU, 4 waves/SIMD.
// progress[blk] = convs completed (RELEASE after barrier drains stores to IC).
// Waiters spin with RELAXED loads. Lockstep bound: co-executing blocks are at
// the SAME conv index; write buffer != read buffer (S->T0->T1->T0->S).
__global__ __launch_bounds__(1024) void ode_persist(
    const unsigned short* __restrict__ wimg,
    const float* __restrict__ b1, const float* __restrict__ b2,
    const float* __restrict__ b3, const float* __restrict__ b4,
    uint32_t* __restrict__ S0, uint32_t* __restrict__ S1,
    uint32_t* __restrict__ T0, uint32_t* __restrict__ T1,
    float* __restrict__ outs, int* progress) {
  extern __shared__ uint8_t lds[];
  const int blk = blockIdx.x;
  const int b = blk >> 4;
  const int rp = blk & 15;
  const int h0 = rp << 1;
  const int nbA = (rp > 0) ? blk - 1 : -1;
  const int nbB = (rp < 15) ? blk + 1 : -1;

  const unsigned short* Wl[4] = {wimg, wimg + 73728, wimg + 147456, wimg + 221184};
  const float* Bl[4] = {b1, b2, b3, b4};

  // zero the pad columns (w1 = 0, 33) of epilogue-written rows 1,2 in BOTH
  // A buffers (they are never re-staged nor epilogue-written; stay zero).
  if (threadIdx.x < 128) {
    int t = threadIdx.x;
    int chunk = t & 7;
    int col = ((t >> 3) & 1) * 33;
    int row = 1 + ((t >> 4) & 1);
    int arr = (t >> 5) & 1;
    int buf = (t >> 6) & 1;
    int pix = row * 34 + col;
    *(int4v*)(lds + buf * A_BUF + arr * A_ARR + pix * 128 +
              ((chunk ^ (pix & 7)) * 16)) = (int4v){0, 0, 0, 0};
  }
  __syncthreads();

  // per-thread RK4 state: 4 outputs at (px = mq*16+lg*4+j, oc = ng*16+lmod)
  const int lane = threadIdx.x & 63;
  const int wv = threadIdx.x >> 6;
  const int mq = wv & 3, ng = wv >> 2;
  const int lmod = lane & 15, lg = lane >> 4;
  float Y[4], R[4];
#pragma unroll
  for (int j = 0; j < 4; ++j) {
    const int e = (b * 1024 + h0 * 32 + mq * 16 + lg * 4 + j) * 64 + ng * 16 + lmod;
    Y[j] = outs[e];                           // exact f32 initial state
    R[j] = 0.f;
  }

  int done = 0;
  int cur = 0;
  for (int step = 1; step <= 18; ++step) {
    for (int sub = 0; sub < 4; ++sub) {
      for (int layer = 0; layer < 4; ++layer) {
        const uint32_t* inP;
        uint32_t* outP;
        int mode;
        float* op = nullptr;
        if (layer == 0) {
          inP = (sub == 0) ? S0 : S1; outP = T0; mode = 0;
        } else if (layer == 1) {
          inP = T0; outP = T1; mode = 0;
        } else if (layer == 2) {
          inP = T1; outP = T0; mode = 0;
        } else {
          inP = T0; outP = (sub == 3) ? S0 : S1; mode = 1 + sub;
          if (sub == 3 && (step & 1) == 0) op = outs + (size_t)(step >> 1) * 262144;
        }
        if (threadIdx.x == 0 && done > 0) {
          if (nbA >= 0)
            while (__hip_atomic_load(&progress[nbA], __ATOMIC_RELAXED,
                                     __HIP_MEMORY_SCOPE_AGENT) < done)
              __builtin_amdgcn_s_sleep(2);
          if (nbB >= 0)
            while (__hip_atomic_load(&progress[nbB], __ATOMIC_RELAXED,
                                     __HIP_MEMORY_SCOPE_AGENT) < done)
              __builtin_amdgcn_s_sleep(2);
        }
        __builtin_amdgcn_sched_barrier(0);
        __syncthreads();

        conv_body(lds, b, h0, cur, done == 0, inP, Wl[layer], Bl[layer], outP,
                  Y, R, op, mode);

        __syncthreads();                      // drains all waves' stores (vmcnt)
        ++done;
        cur ^= 1;
        if (threadIdx.x == 0) {
          __hip_atomic_store(&progress[blk], done, __ATOMIC_RELEASE,
                             __HIP_MEMORY_SCOPE_AGENT);
        }
      }
    }
  }
}

// ---------------- decoder: parity-specialized blocks, LDS weights -------------
// dec_s1: grid = img4 x parity4 x 128 ; block 256 = 8 pos x 32 oc ; wl 32KB
__global__ __launch_bounds__(256) void dec_s1(const float* __restrict__ in,
                                              const float* __restrict__ wt,
                                              const float* __restrict__ bs,
                                              float* __restrict__ out) {
  __shared__ float wl[4][64][32];
  const int tid = threadIdx.x;
  const int bl = blockIdx.x & 127;
  const int par = (blockIdx.x >> 7) & 3;
  const int n = blockIdx.x >> 9;
  const int py = par >> 1, px = par & 1;
#pragma unroll
  for (int k = 0; k < 32; ++k) {
    int s = tid + k * 256;                    // 0..8191
    int oc_ = s & 31, ic = (s >> 5) & 63, tp = s >> 11;
    int kk = (py + 2 * (tp >> 1)) * 4 + (px + 2 * (tp & 1));
    wl[tp][ic][oc_] = wt[(kk * 64 + ic) * 32 + oc_];
  }
  __syncthreads();
  const int oc = tid & 31;
  const int pos = bl * 8 + (tid >> 5);
  const int my = pos >> 5, mx = pos & 31;
  float a = bs[oc];
#pragma unroll
  for (int ay = 0; ay < 2; ++ay) {
    int iy = my + py - 1 + ay;
    if ((unsigned)iy >= 32u) continue;
#pragma unroll
    for (int ax = 0; ax < 2; ++ax) {
      int ix = mx + px - 1 + ax;
      if ((unsigned)ix >= 32u) continue;
      const float4* xp = (const float4*)(in + ((n * 32 + iy) * 32 + ix) * 64);
      const int tp = ay * 2 + ax;
#pragma unroll
      for (int i4 = 0; i4 < 16; ++i4) {
        float4 xv = xp[i4];
        a = fmaf(xv.x, wl[tp][i4 * 4 + 0][oc], a);
        a = fmaf(xv.y, wl[tp][i4 * 4 + 1][oc], a);
        a = fmaf(xv.z, wl[tp][i4 * 4 + 2][oc], a);
        a = fmaf(xv.w, wl[tp][i4 * 4 + 3][oc], a);
      }
    }
  }
  const int oy = 2 * my + py, ox = 2 * mx + px;
  out[((n * 64 + oy) * 64 + ox) * 32 + oc] = (a > 0.f) ? a : 0.2f * a;
}

// dec_s2: grid = img4 x parity4 x 256 ; block 256 = 16 pos x 16 oc ; wl 8KB
__global__ __launch_bounds__(256) void dec_s2(const float* __restrict__ in,
                                              const float* __restrict__ wt,
                                              const float* __restrict__ bs,
                                              float* __restrict__ out) {
  __shared__ float wl[4][32][16];
  const int tid = threadIdx.x;
  const int bl = blockIdx.x & 255;
  const int par = (blockIdx.x >> 8) & 3;
  const int n = blockIdx.x >> 10;
  const int py = par >> 1, px = par & 1;
#pragma unroll
  for (int k = 0; k < 8; ++k) {
    int s = tid + k * 256;                    // 0..2047
    int oc_ = s & 15, ic = (s >> 4) & 31, tp = s >> 9;
    int kk = (py + 2 * (tp >> 1)) * 4 + (px + 2 * (tp & 1));
    wl[tp][ic][oc_] = wt[(kk * 32 + ic) * 16 + oc_];
  }
  __syncthreads();
  const int oc = tid & 15;
  const int pos = bl * 16 + (tid >> 4);
  const int my = pos >> 6, mx = pos & 63;
  float a = bs[oc];
#pragma unroll
  for (int ay = 0; ay < 2; ++ay) {
    int iy = my + py - 1 + ay;
    if ((unsigned)iy >= 64u) continue;
#pragma unroll
    for (int ax = 0; ax < 2; ++ax) {
      int ix = mx + px - 1 + ax;
      if ((unsigned)ix >= 64u) continue;
      const float4* xp = (const float4*)(in + ((n * 64 + iy) * 64 + ix) * 32);
      const int tp = ay * 2 + ax;
#pragma unroll
      for (int i4 = 0; i4 < 8; ++i4) {
        float4 xv = xp[i4];
        a = fmaf(xv.x, wl[tp][i4 * 4 + 0][oc], a);
        a = fmaf(xv.y, wl[tp][i4 * 4 + 1][oc], a);
        a = fmaf(xv.z, wl[tp][i4 * 4 + 2][oc], a);
        a = fmaf(xv.w, wl[tp][i4 * 4 + 3][oc], a);
      }
    }
  }
  const int oy = 2 * my + py, ox = 2 * mx + px;
  out[((n * 128 + oy) * 128 + ox) * 16 + oc] = (a > 0.f) ? a : 0.2f * a;
}

__global__ __launch_bounds__(256) void dec_s3(const float* __restrict__ in,
                                              const float* __restrict__ wt,
                                              const float* __restrict__ bs,
                                              float* __restrict__ out) {
  int t = blockIdx.x * 256 + threadIdx.x;
  int ox = t & 127, oy = (t >> 7) & 127, n = t >> 14;
  float a = bs[0];
#pragma unroll
  for (int ky = 0; ky < 3; ++ky) {
    int iy = oy + ky - 1;
    if ((unsigned)iy >= 128u) continue;
#pragma unroll
    for (int kx = 0; kx < 3; ++kx) {
      int ix = ox + kx - 1;
      if ((unsigned)ix >= 128u) continue;
      const float4* xp = (const float4*)(in + ((n * 128 + iy) * 128 + ix) * 16);
      const float4* wp = (const float4*)(wt + (ky * 3 + kx) * 16);
#pragma unroll
      for (int i4 = 0; i4 < 4; ++i4) {
        float4 xv = xp[i4], wv = wp[i4];
        a = fmaf(xv.x, wv.x, a);
        a = fmaf(xv.y, wv.y, a);
        a = fmaf(xv.z, wv.z, a);
        a = fmaf(xv.w, wv.w, a);
      }
    }
  }
  out[n * 16384 + oy * 128 + ox] = a;
}

// ---------------- host ----------------
extern "C" void kernel_launch(void* const* d_in, const int* in_sizes, int n_in,
                              void* d_out, int out_size, void* d_ws, size_t ws_size,
                              hipStream_t stream) {
  (void)in_sizes; (void)n_in; (void)out_size; (void)ws_size;
  (void)hipFuncSetAttribute((const void*)ode_persist,
                            hipFuncAttributeMaxDynamicSharedMemorySize, CONV_LDS);

  uint8_t* ws = (uint8_t*)d_ws;
  uint32_t* S0 = (uint32_t*)(ws + 0);         // packed state, 1 MB each
  uint32_t* S1 = (uint32_t*)(ws + 1048576);
  uint32_t* T0 = (uint32_t*)(ws + 2097152);
  uint32_t* T1 = (uint32_t*)(ws + 3145728);
  unsigned short* WIMG = (unsigned short*)(ws + 4194304);   // 589824 B
  float* s1wt = (float*)(ws + 4784128);
  float* s2wt = (float*)(ws + 4915200);
  float* s3wt = (float*)(ws + 4947968);
  int* progress = (int*)(ws + 4980736);       // 64 x int
  float* outs = (float*)(ws + 5242880);       // 10 x 262144 f32
  float* d1 = (float*)(ws + 16777216);        // decoder scratch 2 MB
  float* d2 = (float*)(ws + 18874368);        // decoder scratch 4 MB

  const float* h_s0 = (const float*)d_in[0];
  const float* wode[4] = {(const float*)d_in[1], (const float*)d_in[3],
                          (const float*)d_in[5], (const float*)d_in[7]};
  const float* bode[4] = {(const float*)d_in[2], (const float*)d_in[4],
                          (const float*)d_in[6], (const float*)d_in[8]};
  const float* s1w = (const float*)d_in[9];
  const float* s1b = (const float*)d_in[10];
  const float* s2w = (const float*)d_in[11];
  const float* s2b = (const float*)d_in[12];
  const float* s3w = (const float*)d_in[13];
  const float* s3b = (const float*)d_in[14];

  (void)hipMemsetAsync(progress, 0, 64 * sizeof(int), stream);
  prep_weights<<<737, 256, 0, stream>>>(wode[0], wode[1], wode[2], wode[3],
                                        s1w, s2w, s3w, WIMG, s1wt, s2wt, s3wt);
  prep_state<<<1024, 256, 0, stream>>>(h_s0, S0, outs);

  ode_persist<<<dim3(64), dim3(1024), CONV_LDS, stream>>>(
      WIMG, bode[0], bode[1], bode[2], bode[3],
      S0, S1, T0, T1, outs, progress);

  for (int t0 = 0; t0 < 10; ++t0) {
    dec_s1<<<2048, 256, 0, stream>>>(outs + (size_t)t0 * 262144, s1wt, s1b, d1);
    dec_s2<<<4096, 256, 0, stream>>>(d1, s2wt, s2b, d2);
    dec_s3<<<256, 256, 0, stream>>>(d2, s3wt, s3b,
                                    (float*)d_out + (size_t)t0 * 65536);
  }
}